// Round 1
// baseline (1700.465 us; speedup 1.0000x reference)
//
#include <hip/hip_runtime.h>
#include <math.h>

// EGNN layer, fp32. Structure:
//   kernel 1 (tdst):  T[n]  = hidden[n] @ W1[128:256,:] + b1          (per-node, shared by its 16 in-edges)
//   kernel 2 (edge):  per edge: m1=tanh(hsrc@W1[0:128,:] + T[dst] + l2*W1[256,:])
//                     m2=tanh(m1@W2+b2); m=sigmoid(m2.Wa+ba)*m2
//                     c1=tanh(m@Wc1+bc1); c2=tanh(c1.Wc2); ct=cd*c2
//                     block-local reductions -> coords_out, m_i (ws)
//   kernel 3 (node):  h=tanh([hidden,m_i]@Wh1+bh1)@Wh2+bh2; hidden_out=hidden+h
//
// Key codegen idea: thread == row (edge/node). acc[128] in VGPRs (static
// indexing only); the K-dim activation row in LDS ([row][132] f32 — +4 pad so
// wave64 ds_read_b128 at stride 132 words is bank-conflict-free); weights are
// wave-uniform -> compiler emits s_load (scalar cache), one W word per v_fmac.

#ifndef EGC_CONSTS
#define EGC_CONSTS
#endif

#if defined(__has_builtin)
#  if __has_builtin(__builtin_amdgcn_exp2f)
#    define EXP2F(x) __builtin_amdgcn_exp2f(x)
#  else
#    define EXP2F(x) exp2f(x)
#  endif
#  if __has_builtin(__builtin_amdgcn_rcpf)
#    define RCPF(x) __builtin_amdgcn_rcpf(x)
#  else
#    define RCPF(x) (1.0f/(x))
#  endif
#else
#  define EXP2F(x) exp2f(x)
#  define RCPF(x) (1.0f/(x))
#endif

#define DEVFN static __device__ __forceinline__

DEVFN float ftanh(float x) {
  // tanh(x) = 1 - 2/(e^{2x}+1); e^{2x} = 2^{x * 2*log2(e)}
  float e = EXP2F(x * 2.8853900817779268f);
  return 1.0f - 2.0f * RCPF(e + 1.0f);   // saturates correctly at +/-inf
}

DEVFN float fsigmoid(float x) {
  float e = EXP2F(-x * 1.4426950408889634f);
  return RCPF(1.0f + e);
}

// acc[c*32+j] += xrow[k] * W[k*128 + c*32 + j], k = 0 .. 4*K4-1.
// W index is wave-uniform -> s_load. xrow is this thread's private LDS row.
template<int K4>
DEVFN void mlp_layer(float (&acc)[128], const float4* __restrict__ xrow,
                     const float* __restrict__ W) {
#pragma unroll
  for (int c = 0; c < 4; ++c) {
#pragma unroll 2
    for (int k4 = 0; k4 < K4; ++k4) {
      const float4 xv = xrow[k4];
#pragma unroll
      for (int kk = 0; kk < 4; ++kk) {
        const float xs = (kk == 0) ? xv.x : (kk == 1) ? xv.y : (kk == 2) ? xv.z : xv.w;
        const float* Wk = W + (k4 * 4 + kk) * 128 + c * 32;
#pragma unroll
        for (int j = 0; j < 32; ++j)
          acc[c * 32 + j] = fmaf(xs, Wk[j], acc[c * 32 + j]);
      }
    }
  }
}

DEVFN void tanh_all(float (&acc)[128]) {
#pragma unroll
  for (int j = 0; j < 128; ++j) acc[j] = ftanh(acc[j]);
}

DEVFN void init_bias(float (&acc)[128], const float* __restrict__ b) {
#pragma unroll
  for (int j = 0; j < 128; ++j) acc[j] = b[j];   // uniform -> s_load
}

DEVFN void store_row(float4* __restrict__ dst, const float (&acc)[128]) {
#pragma unroll
  for (int q = 0; q < 32; ++q)
    dst[q] = make_float4(acc[4*q], acc[4*q+1], acc[4*q+2], acc[4*q+3]);
}

DEVFN float dot128(const float (&a)[128], const float* __restrict__ w) {
  float p0 = 0.f, p1 = 0.f, p2 = 0.f, p3 = 0.f;
#pragma unroll
  for (int j = 0; j < 128; j += 4) {
    p0 = fmaf(a[j+0], w[j+0], p0);
    p1 = fmaf(a[j+1], w[j+1], p1);
    p2 = fmaf(a[j+2], w[j+2], p2);
    p3 = fmaf(a[j+3], w[j+3], p3);
  }
  return (p0 + p1) + (p2 + p3);
}

// ---------------- kernel 1: T[n] = hidden[n] @ W1b + b1 ----------------
__global__ __launch_bounds__(64) void tdst_kernel(
    const float* __restrict__ hidden, const float* __restrict__ W1,
    const float* __restrict__ b1, float* __restrict__ T, int N) {
  __shared__ __align__(16) float hbuf[64 * 132];
  const int t  = threadIdx.x;
  const int n0 = blockIdx.x * 64;
#pragma unroll 4
  for (int r = 0; r < 64; ++r) {
    const int g = n0 + r;
    float2 v = make_float2(0.f, 0.f);
    if (g < N) v = ((const float2*)(hidden + (size_t)g * 128))[t];
    *(float2*)&hbuf[r * 132 + 2 * t] = v;
  }
  __syncthreads();
  float acc[128];
  init_bias(acc, b1);
  mlp_layer<32>(acc, (const float4*)&hbuf[t * 132], W1 + 128 * 128);  // W1 rows 128..255
  store_row((float4*)&hbuf[t * 132], acc);   // own row only
  __syncthreads();
#pragma unroll 4
  for (int r = 0; r < 64; ++r) {
    const int g = n0 + r;
    if (g < N)
      ((float2*)(T + (size_t)g * 128))[t] = *(const float2*)&hbuf[r * 132 + 2 * t];
  }
}

// ---------------- kernel 2: edge MLP + reductions ----------------
// 64 threads = 64 edges = 4 nodes per block (edges are grouped 16-per-dst).
__global__ __launch_bounds__(64) void edge_kernel(
    const float* __restrict__ coords, const float* __restrict__ hidden,
    const int* __restrict__ edges,
    const float* __restrict__ W1, const float* __restrict__ W2,
    const float* __restrict__ b2, const float* __restrict__ Wa,
    const float* __restrict__ ba, const float* __restrict__ Wc1,
    const float* __restrict__ bc1, const float* __restrict__ Wc2,
    const float* __restrict__ T, float* __restrict__ mi,
    float* __restrict__ coords_out, int E) {
  __shared__ __align__(16) float xbuf[64 * 132];
  __shared__ int sbuf[64];
  const int t = threadIdx.x;
  const int e = blockIdx.x * 64 + t;
  const int src = edges[e];
  const int dst = edges[E + e];

  const float cdx = coords[3 * dst], cdy = coords[3 * dst + 1], cdz = coords[3 * dst + 2];
  const float dx = coords[3 * src] - cdx;
  const float dy = coords[3 * src + 1] - cdy;
  const float dz = coords[3 * src + 2] - cdz;
  const float l2 = sqrtf(dx * dx + dy * dy + dz * dz);

  sbuf[t] = src;
  __syncthreads();
  // stage hidden[src] rows cooperatively (coalesced 512B/row)
#pragma unroll 4
  for (int r = 0; r < 64; ++r) {
    const float2 v = ((const float2*)(hidden + (size_t)sbuf[r] * 128))[t];
    *(float2*)&xbuf[r * 132 + 2 * t] = v;
  }
  __syncthreads();

  const float4* xrow  = (const float4*)&xbuf[t * 132];
  float4*       xroww = (float4*)&xbuf[t * 132];
  float acc[128];

  // ---- layer 1: tanh(hsrc@W1a + T[dst] + l2*W1[256,:]) ----
  {
    const float4* Tr = (const float4*)(T + (size_t)dst * 128);
    const float4* Wl = (const float4*)(W1 + 256 * 128);
#pragma unroll
    for (int q = 0; q < 32; ++q) {
      const float4 tv = Tr[q];
      const float4 wv = Wl[q];
      acc[4*q+0] = fmaf(l2, wv.x, tv.x);
      acc[4*q+1] = fmaf(l2, wv.y, tv.y);
      acc[4*q+2] = fmaf(l2, wv.z, tv.z);
      acc[4*q+3] = fmaf(l2, wv.w, tv.w);
    }
  }
  mlp_layer<32>(acc, xrow, W1);        // W1 rows 0..127
  tanh_all(acc);
  store_row(xroww, acc);               // m1 (own row)

  // ---- layer 2 + attention gate ----
  init_bias(acc, b2);
  mlp_layer<32>(acc, xrow, W2);
  tanh_all(acc);
  const float g = fsigmoid(dot128(acc, Wa) + ba[0]);
#pragma unroll
  for (int j = 0; j < 128; ++j) acc[j] *= g;
  store_row(xroww, acc);               // gated m (own row) — kept for m_i

  // ---- coord branch ----
  init_bias(acc, bc1);
  mlp_layer<32>(acc, xrow, Wc1);
  tanh_all(acc);
  const float c2 = ftanh(dot128(acc, Wc2));
  float tx = dx * c2, ty = dy * c2, tz = dz * c2;
#pragma unroll
  for (int m = 1; m <= 8; m <<= 1) {
    tx += __shfl_xor(tx, m, 64);
    ty += __shfl_xor(ty, m, 64);
    tz += __shfl_xor(tz, m, 64);
  }
  if ((t & 15) == 0) {                 // one lane per dst group; indeg == 16
    coords_out[3 * dst + 0] = cdx + tx * 0.0625f;
    coords_out[3 * dst + 1] = cdy + ty * 0.0625f;
    coords_out[3 * dst + 2] = cdz + tz * 0.0625f;
  }
  __syncthreads();                     // all gated-m rows in LDS before cross-row reads

  // ---- m_i = sum of gated m over the 16 edges of each node ----
  {
    const int nl = t >> 4;             // local node 0..3
    const int c0 = (t & 15) * 8;       // 8 cols per thread
    const int nodeg = __shfl(dst, nl << 4, 64);
    float4 s0 = make_float4(0.f, 0.f, 0.f, 0.f), s1 = s0;
#pragma unroll
    for (int r = 0; r < 16; ++r) {
      const float* row = &xbuf[(nl * 16 + r) * 132 + c0];
      const float4 a = *(const float4*)row;
      const float4 b = *(const float4*)(row + 4);
      s0.x += a.x; s0.y += a.y; s0.z += a.z; s0.w += a.w;
      s1.x += b.x; s1.y += b.y; s1.z += b.z; s1.w += b.w;
    }
    float* o = mi + (size_t)nodeg * 128 + c0;
    *(float4*)o       = s0;
    *(float4*)(o + 4) = s1;
  }
}

// ---------------- kernel 3: node update MLP ----------------
__global__ __launch_bounds__(64) void node_kernel(
    const float* __restrict__ hidden, const float* __restrict__ mi,
    const float* __restrict__ Wh1, const float* __restrict__ bh1,
    const float* __restrict__ Wh2, const float* __restrict__ bh2,
    float* __restrict__ hidden_out, int N) {
  __shared__ __align__(16) float buf[64 * 132];
  const int t  = threadIdx.x;
  const int n0 = blockIdx.x * 64;
  // stage hidden rows
#pragma unroll 4
  for (int r = 0; r < 64; ++r) {
    const int g = n0 + r;
    float2 v = make_float2(0.f, 0.f);
    if (g < N) v = ((const float2*)(hidden + (size_t)g * 128))[t];
    *(float2*)&buf[r * 132 + 2 * t] = v;
  }
  __syncthreads();
  float acc[128];
  init_bias(acc, bh1);
  mlp_layer<32>(acc, (const float4*)&buf[t * 132], Wh1);          // k = 0..127 (hidden part)
  __syncthreads();                                                // done with hidden rows
  // stage m_i rows into the same buffer
#pragma unroll 4
  for (int r = 0; r < 64; ++r) {
    const int g = n0 + r;
    float2 v = make_float2(0.f, 0.f);
    if (g < N) v = ((const float2*)(mi + (size_t)g * 128))[t];
    *(float2*)&buf[r * 132 + 2 * t] = v;
  }
  __syncthreads();
  mlp_layer<32>(acc, (const float4*)&buf[t * 132], Wh1 + 128 * 128); // k = 128..255 (m_i part)
  tanh_all(acc);
  store_row((float4*)&buf[t * 132], acc);                          // h1 (own row)
  init_bias(acc, bh2);
  mlp_layer<32>(acc, (const float4*)&buf[t * 132], Wh2);
  store_row((float4*)&buf[t * 132], acc);                          // h2 (own row)
  __syncthreads();
  // residual + coalesced store
#pragma unroll 4
  for (int r = 0; r < 64; ++r) {
    const int g = n0 + r;
    if (g < N) {
      const float2 h = ((const float2*)(hidden + (size_t)g * 128))[t];
      const float2 v = *(const float2*)&buf[r * 132 + 2 * t];
      ((float2*)(hidden_out + (size_t)g * 128))[t] = make_float2(h.x + v.x, h.y + v.y);
    }
  }
}

extern "C" void kernel_launch(void* const* d_in, const int* in_sizes, int n_in,
                              void* d_out, int out_size, void* d_ws, size_t ws_size,
                              hipStream_t stream) {
  const float* coords = (const float*)d_in[0];
  const float* hidden = (const float*)d_in[1];
  const int*   edges  = (const int*)d_in[2];
  const float* W1  = (const float*)d_in[3];
  const float* b1  = (const float*)d_in[4];
  const float* W2  = (const float*)d_in[5];
  const float* b2  = (const float*)d_in[6];
  const float* Wa  = (const float*)d_in[7];
  const float* ba  = (const float*)d_in[8];
  const float* Wc1 = (const float*)d_in[9];
  const float* bc1 = (const float*)d_in[10];
  const float* Wc2 = (const float*)d_in[11];
  const float* Wh1 = (const float*)d_in[12];
  const float* bh1 = (const float*)d_in[13];
  const float* Wh2 = (const float*)d_in[14];
  const float* bh2 = (const float*)d_in[15];

  const int N = in_sizes[0] / 3;    // 30000
  const int E = in_sizes[2] / 2;    // 480000 (divisible by 64)

  float* T  = (float*)d_ws;                   // [N,128]
  float* mi = T + (size_t)N * 128;            // [N,128]
  float* coords_out = (float*)d_out;          // [N,3]
  float* hidden_out = coords_out + (size_t)N * 3;  // [N,128]

  const int nodeBlocks = (N + 63) / 64;
  tdst_kernel<<<nodeBlocks, 64, 0, stream>>>(hidden, W1, b1, T, N);
  edge_kernel<<<E / 64, 64, 0, stream>>>(coords, hidden, edges, W1, W2, b2,
                                         Wa, ba, Wc1, bc1, Wc2, T, mi,
                                         coords_out, E);
  node_kernel<<<nodeBlocks, 64, 0, stream>>>(hidden, mi, Wh1, bh1, Wh2, bh2,
                                             hidden_out, N);
}

// Round 2
// 760.916 us; speedup vs baseline: 2.2348x; 2.2348x over previous
//
#include <hip/hip_runtime.h>
#include <math.h>

// EGNN layer via split-bf16 MFMA (gfx950).
//   x = hi + lo (two bf16); X@W = Ah*Bh + Al*Bh + Ah*Bl accumulated in fp32
//   -> ~fp32-quality results on the 2.5PF matrix pipe.
// Kernels:
//   wconv: fp32 weights -> bf16 hi/lo MFMA B-fragment layout (device array)
//   tdst : T[n] = hidden[n] @ W1[128:256] + b1              (per-node bias reused by 16 edges)
//   edge : m1 = tanh(hsrc@W1a + T[dst] + l2*w_l2); m2 = tanh(m1@W2 + b2)
//          m = sigmoid(m2.Wa+ba)*m2; c1 = tanh(m@Wc1+bc1); c2 = tanh(c1.Wc2)
//          coords_out (in-wave segment sum, indeg=16), mi[dst] = sum m
//   node : h = tanh([hidden|mi]@Wh1+bh1)@Wh2 + bh2; hidden_out = hidden + h
// Geometry: 1 wave/block, M=64 rows/wave, N=128 -> acc = 4x8 f32x4 tiles.
// Activations bounce through swizzled fp32 LDS (byte ^ ((row&7)<<4)) so
// ds_read_b128 A-frags and scatter writes are bank-conflict-free.

typedef __attribute__((ext_vector_type(8))) short short8;
typedef __attribute__((ext_vector_type(4))) float f32x4;

#define MFMA_BF16 __builtin_amdgcn_mfma_f32_16x16x32_bf16

// frag offsets in u16 units: per matrix-plane KT*8*64*8 elems (KT=K/32)
#define OFF_W1A_HI 0
#define OFF_W1A_LO 16384
#define OFF_W1B_HI 32768
#define OFF_W1B_LO 49152
#define OFF_W2_HI  65536
#define OFF_W2_LO  81920
#define OFF_WC1_HI 98304
#define OFF_WC1_LO 114688
#define OFF_WH1_HI 131072
#define OFF_WH1_LO 163840
#define OFF_WH2_HI 196608
#define OFF_WH2_LO 212992
#define FRAG_TOTAL 229376

__device__ __align__(16) unsigned short g_frags[FRAG_TOTAL];

#define DEVFN static __device__ __forceinline__

DEVFN unsigned short f2bf(float x) {              // fp32 -> bf16 RNE
  unsigned int u = __float_as_uint(x);
  u += 0x7fffu + ((u >> 16) & 1u);
  return (unsigned short)(u >> 16);
}
DEVFN float bf2f(unsigned short h) { return __uint_as_float(((unsigned int)h) << 16); }

DEVFN float ftanh(float x) {                      // tanh = 1 - 2/(e^{2x}+1)
  float e = exp2f(x * 2.8853900817779268f);
  return 1.0f - 2.0f * __builtin_amdgcn_rcpf(e + 1.0f);
}
DEVFN float fsigmoid(float x) {
  float e = exp2f(-x * 1.4426950408889634f);
  return __builtin_amdgcn_rcpf(1.0f + e);
}

DEVFN void mk_frag(const float* __restrict__ x, short8& hi, short8& lo) {
#pragma unroll
  for (int j = 0; j < 8; ++j) {
    unsigned short h = f2bf(x[j]);
    hi[j] = (short)h;
    lo[j] = (short)f2bf(x[j] - bf2f(h));
  }
}

DEVFN f32x4 mfma3(short8 ah, short8 al, short8 bh, short8 bl, f32x4 c) {
  c = MFMA_BF16(ah, bh, c, 0, 0, 0);
  c = MFMA_BF16(al, bh, c, 0, 0, 0);
  c = MFMA_BF16(ah, bl, c, 0, 0, 0);
  return c;
}

DEVFN short8 ldfrag(int off_u16, int kt, int nt, int lane) {
  return *(const short8*)(g_frags + off_u16 + (((kt * 8 + nt) * 64 + lane) << 3));
}

// swizzled LDS index (word units): byte ^ ((row&7)<<4)
DEVFN int xidx(int row, int word) { return (row << 7) + (word ^ ((row & 7) << 2)); }

// ---------------- weight -> fragment conversion ----------------
__global__ __launch_bounds__(256) void wconv_kernel(const float* __restrict__ W, int KT,
                                                    int offHi, int offLo) {
  int t = blockIdx.x * 256 + threadIdx.x;
  if (t >= KT * 4096) return;
  int j = t & 7, lane = (t >> 3) & 63, nt = (t >> 9) & 7, kt = t >> 12;
  int k = kt * 32 + ((lane >> 4) << 3) + j;
  int n = nt * 16 + (lane & 15);
  float w = W[k * 128 + n];
  unsigned short h = f2bf(w);
  g_frags[offHi + t] = h;
  g_frags[offLo + t] = f2bf(w - bf2f(h));
}

// 4 ksteps of [64x128]@[128x128] with A from global fp32 rows (rofs = row*128 elem offsets)
#define GEMM_GBL(base, rofs, koff, OFFH, OFFL, ktbase)                          \
  {                                                                             \
    _Pragma("unroll") for (int ks = 0; ks < 4; ++ks) {                          \
      short8 ah[4], al[4];                                                      \
      _Pragma("unroll") for (int rt = 0; rt < 4; ++rt) {                        \
        const float* p = (base) + (rofs)[rt] + (koff) + ks * 32 + kg;           \
        float x[8];                                                             \
        *(f32x4*)&x[0] = *(const f32x4*)p;                                      \
        *(f32x4*)&x[4] = *(const f32x4*)(p + 4);                                \
        mk_frag(x, ah[rt], al[rt]);                                             \
      }                                                                         \
      _Pragma("unroll") for (int nt = 0; nt < 8; ++nt) {                        \
        short8 bh = ldfrag(OFFH, (ktbase) + ks, nt, lane);                      \
        short8 bl = ldfrag(OFFL, (ktbase) + ks, nt, lane);                      \
        _Pragma("unroll") for (int rt = 0; rt < 4; ++rt)                        \
            acc[rt][nt] = mfma3(ah[rt], al[rt], bh, bl, acc[rt][nt]);           \
      }                                                                         \
    }                                                                           \
  }

// full [64x128]@[128x128] with A from swizzled LDS fp32
#define GEMM_LDS(Xs, OFFH, OFFL)                                                \
  {                                                                             \
    _Pragma("unroll") for (int ks = 0; ks < 4; ++ks) {                          \
      short8 ah[4], al[4];                                                      \
      _Pragma("unroll") for (int rt = 0; rt < 4; ++rt) {                        \
        int row = rt * 16 + (lane & 15);                                        \
        int w0 = ks * 32 + kg;                                                  \
        float x[8];                                                             \
        *(f32x4*)&x[0] = *(const f32x4*)&(Xs)[xidx(row, w0)];                   \
        *(f32x4*)&x[4] = *(const f32x4*)&(Xs)[xidx(row, w0 + 4)];               \
        mk_frag(x, ah[rt], al[rt]);                                             \
      }                                                                         \
      _Pragma("unroll") for (int nt = 0; nt < 8; ++nt) {                        \
        short8 bh = ldfrag(OFFH, ks, nt, lane);                                 \
        short8 bl = ldfrag(OFFL, ks, nt, lane);                                 \
        _Pragma("unroll") for (int rt = 0; rt < 4; ++rt)                        \
            acc[rt][nt] = mfma3(ah[rt], al[rt], bh, bl, acc[rt][nt]);           \
      }                                                                         \
    }                                                                           \
  }

#define ZERO_ACC                                                                \
  _Pragma("unroll") for (int rt = 0; rt < 4; ++rt)                              \
  _Pragma("unroll") for (int nt = 0; nt < 8; ++nt) acc[rt][nt] = vzero;

// ---------------- tdst: T = hidden @ W1b + b1 ----------------
__global__ __launch_bounds__(64) void tdst_kernel(const float* __restrict__ hidden,
                                                  const float* __restrict__ b1,
                                                  float* __restrict__ T, int N) {
  __shared__ __align__(16) float Xs[64 * 128];
  __shared__ float sb[128];
  const int lane = threadIdx.x;
  const int n0 = blockIdx.x * 64;
  const int kg = (lane >> 4) << 3;
  sb[lane] = b1[lane];
  sb[lane + 64] = b1[lane + 64];
  __syncthreads();
  int rofs[4];
#pragma unroll
  for (int rt = 0; rt < 4; ++rt) rofs[rt] = min(n0 + rt * 16 + (lane & 15), N - 1) * 128;
  const f32x4 vzero = {0.f, 0.f, 0.f, 0.f};
  f32x4 acc[4][8];
  ZERO_ACC;
  GEMM_GBL(hidden, rofs, 0, OFF_W1B_HI, OFF_W1B_LO, 0);
  const int cc = lane & 15;
#pragma unroll
  for (int rt = 0; rt < 4; ++rt)
#pragma unroll
    for (int nt = 0; nt < 8; ++nt) {
      float bv = sb[nt * 16 + cc];
#pragma unroll
      for (int reg = 0; reg < 4; ++reg) {
        int row = rt * 16 + ((lane >> 4) << 2) + reg;
        Xs[xidx(row, nt * 16 + cc)] = acc[rt][nt][reg] + bv;
      }
    }
  __syncthreads();
#pragma unroll 4
  for (int i = 0; i < 32; ++i) {
    int f = i * 64 + lane, row = f >> 5, c4 = f & 31;
    int gr = n0 + row;
    if (gr < N)
      *(f32x4*)&T[(size_t)gr * 128 + c4 * 4] = *(const f32x4*)&Xs[xidx(row, c4 * 4)];
  }
}

// ---------------- edge kernel ----------------
__global__ __launch_bounds__(64) void edge_kernel(
    const float* __restrict__ coords, const float* __restrict__ hidden,
    const int* __restrict__ edges, const float* __restrict__ W1,
    const float* __restrict__ Wa, const float* __restrict__ ba,
    const float* __restrict__ b2, const float* __restrict__ bc1,
    const float* __restrict__ Wc2, const float* __restrict__ T,
    float* __restrict__ mi, float* __restrict__ coords_out, int E) {
  __shared__ __align__(16) float Xs[64 * 128];
  __shared__ __align__(16) float smeta[64][4];  // dx,dy,dz,l2
  __shared__ float sT[4 * 128];
  __shared__ float swl2[128], swa[128], swc2[128], sb2[128], sbc1[128];
  __shared__ int ssrc[64];
  __shared__ int sdst[4];

  const int lane = threadIdx.x;
  const int e = blockIdx.x * 64 + lane;
  const int kg = (lane >> 4) << 3;
  const int cc = lane & 15;
  {
    int src = edges[e], dst = edges[E + e];
    float cx = coords[3 * dst], cy = coords[3 * dst + 1], cz = coords[3 * dst + 2];
    float dx = coords[3 * src] - cx, dy = coords[3 * src + 1] - cy, dz = coords[3 * src + 2] - cz;
    smeta[lane][0] = dx; smeta[lane][1] = dy; smeta[lane][2] = dz;
    smeta[lane][3] = sqrtf(dx * dx + dy * dy + dz * dz);
    ssrc[lane] = src * 128;
    if ((lane & 15) == 0) sdst[lane >> 4] = dst;
    swl2[lane] = W1[256 * 128 + lane]; swl2[lane + 64] = W1[256 * 128 + lane + 64];
    swa[lane] = Wa[lane];              swa[lane + 64] = Wa[lane + 64];
    swc2[lane] = Wc2[lane];            swc2[lane + 64] = Wc2[lane + 64];
    sb2[lane] = b2[lane];              sb2[lane + 64] = b2[lane + 64];
    sbc1[lane] = bc1[lane];            sbc1[lane + 64] = bc1[lane + 64];
  }
  const float ba_s = ba[0];
  __syncthreads();
  {  // stage T rows of the 4 dsts
    int rtl = lane >> 4, c0 = (lane & 15) * 8;
    const float* Tp = T + (size_t)sdst[rtl] * 128 + c0;
    *(f32x4*)&sT[rtl * 128 + c0] = *(const f32x4*)Tp;
    *(f32x4*)&sT[rtl * 128 + c0 + 4] = *(const f32x4*)(Tp + 4);
  }
  __syncthreads();

  const f32x4 vzero = {0.f, 0.f, 0.f, 0.f};
  f32x4 acc[4][8];
  ZERO_ACC;

  // ---- layer 1: A = hidden[src] ----
  int rofs[4];
#pragma unroll
  for (int rt = 0; rt < 4; ++rt) rofs[rt] = ssrc[rt * 16 + (lane & 15)];
  GEMM_GBL(hidden, rofs, 0, OFF_W1A_HI, OFF_W1A_LO, 0);
  {  // epi1: tanh(acc + T + l2*wl2) -> Xs
    float wl2c[8];
#pragma unroll
    for (int nt = 0; nt < 8; ++nt) wl2c[nt] = swl2[nt * 16 + cc];
#pragma unroll
    for (int rt = 0; rt < 4; ++rt) {
      float l2r[4];
#pragma unroll
      for (int reg = 0; reg < 4; ++reg) l2r[reg] = smeta[rt * 16 + ((lane >> 4) << 2) + reg][3];
#pragma unroll
      for (int nt = 0; nt < 8; ++nt) {
        float tv = sT[rt * 128 + nt * 16 + cc];
#pragma unroll
        for (int reg = 0; reg < 4; ++reg) {
          float v = ftanh(acc[rt][nt][reg] + tv + l2r[reg] * wl2c[nt]);
          int row = rt * 16 + ((lane >> 4) << 2) + reg;
          Xs[xidx(row, nt * 16 + cc)] = v;
        }
      }
    }
  }

  // ---- layer 2: m2 = tanh(m1@W2+b2); gate ----
  ZERO_ACC;
  GEMM_LDS(Xs, OFF_W2_HI, OFF_W2_LO);
  {
    float wac[8], b2c[8];
#pragma unroll
    for (int nt = 0; nt < 8; ++nt) { wac[nt] = swa[nt * 16 + cc]; b2c[nt] = sb2[nt * 16 + cc]; }
#pragma unroll
    for (int rt = 0; rt < 4; ++rt)
#pragma unroll
      for (int nt = 0; nt < 8; ++nt)
#pragma unroll
        for (int reg = 0; reg < 4; ++reg)
          acc[rt][nt][reg] = ftanh(acc[rt][nt][reg] + b2c[nt]);
    float p[4][4];
#pragma unroll
    for (int rt = 0; rt < 4; ++rt)
#pragma unroll
      for (int reg = 0; reg < 4; ++reg) {
        float s = 0.f;
#pragma unroll
        for (int nt = 0; nt < 8; ++nt) s = fmaf(acc[rt][nt][reg], wac[nt], s);
        p[rt][reg] = s;
      }
#pragma unroll
    for (int m = 1; m <= 8; m <<= 1)
#pragma unroll
      for (int rt = 0; rt < 4; ++rt)
#pragma unroll
        for (int reg = 0; reg < 4; ++reg) p[rt][reg] += __shfl_xor(p[rt][reg], m);
#pragma unroll
    for (int rt = 0; rt < 4; ++rt)
#pragma unroll
      for (int reg = 0; reg < 4; ++reg) {
        float g = fsigmoid(p[rt][reg] + ba_s);
#pragma unroll
        for (int nt = 0; nt < 8; ++nt) acc[rt][nt][reg] *= g;
      }
    // m_i column sums (16 rows of each dst live in this wave)
    float cs[4][8];
#pragma unroll
    for (int rt = 0; rt < 4; ++rt)
#pragma unroll
      for (int nt = 0; nt < 8; ++nt)
        cs[rt][nt] = (acc[rt][nt][0] + acc[rt][nt][1]) + (acc[rt][nt][2] + acc[rt][nt][3]);
#pragma unroll
    for (int m = 16; m <= 32; m <<= 1)
#pragma unroll
      for (int rt = 0; rt < 4; ++rt)
#pragma unroll
        for (int nt = 0; nt < 8; ++nt) cs[rt][nt] += __shfl_xor(cs[rt][nt], m);
    if (lane < 16) {
#pragma unroll
      for (int rt = 0; rt < 4; ++rt) {
        size_t d = (size_t)sdst[rt] * 128;
#pragma unroll
        for (int nt = 0; nt < 8; ++nt) mi[d + nt * 16 + lane] = cs[rt][nt];
      }
    }
    // gated m -> Xs
#pragma unroll
    for (int rt = 0; rt < 4; ++rt)
#pragma unroll
      for (int nt = 0; nt < 8; ++nt)
#pragma unroll
        for (int reg = 0; reg < 4; ++reg) {
          int row = rt * 16 + ((lane >> 4) << 2) + reg;
          Xs[xidx(row, nt * 16 + cc)] = acc[rt][nt][reg];
        }
  }

  // ---- layer 3: c1 = tanh(m@Wc1+bc1); c2 = tanh(c1.Wc2); coords ----
  ZERO_ACC;
  GEMM_LDS(Xs, OFF_WC1_HI, OFF_WC1_LO);
  {
    float wcc[8], bcc[8];
#pragma unroll
    for (int nt = 0; nt < 8; ++nt) { wcc[nt] = swc2[nt * 16 + cc]; bcc[nt] = sbc1[nt * 16 + cc]; }
    float p[4][4];
#pragma unroll
    for (int rt = 0; rt < 4; ++rt)
#pragma unroll
      for (int reg = 0; reg < 4; ++reg) {
        float s = 0.f;
#pragma unroll
        for (int nt = 0; nt < 8; ++nt)
          s = fmaf(ftanh(acc[rt][nt][reg] + bcc[nt]), wcc[nt], s);
        p[rt][reg] = s;
      }
#pragma unroll
    for (int m = 1; m <= 8; m <<= 1)
#pragma unroll
      for (int rt = 0; rt < 4; ++rt)
#pragma unroll
        for (int reg = 0; reg < 4; ++reg) p[rt][reg] += __shfl_xor(p[rt][reg], m);
    const float* sm = &smeta[0][0];
    float st[4];
#pragma unroll
    for (int rt = 0; rt < 4; ++rt) {
      float s = 0.f;
#pragma unroll
      for (int reg = 0; reg < 4; ++reg) {
        float c2 = ftanh(p[rt][reg]);
        s = fmaf(sm[(rt * 16 + ((lane >> 4) << 2) + reg) * 4 + (cc & 3)], c2, s);
      }
      st[rt] = s;
    }
#pragma unroll
    for (int rt = 0; rt < 4; ++rt) { st[rt] += __shfl_xor(st[rt], 16); st[rt] += __shfl_xor(st[rt], 32); }
    if (lane < 3) {
#pragma unroll
      for (int rt = 0; rt < 4; ++rt) {
        int d = sdst[rt];
        coords_out[d * 3 + lane] = coords[d * 3 + lane] + st[rt] * 0.0625f;
      }
    }
  }
}

// ---------------- node kernel ----------------
__global__ __launch_bounds__(64) void node_kernel(const float* __restrict__ hidden,
                                                  const float* __restrict__ mi,
                                                  const float* __restrict__ bh1,
                                                  const float* __restrict__ bh2,
                                                  float* __restrict__ hidden_out, int N) {
  __shared__ __align__(16) float Xs[64 * 128];
  __shared__ float sb1[128], sb2v[128];
  const int lane = threadIdx.x;
  const int n0 = blockIdx.x * 64;
  const int kg = (lane >> 4) << 3;
  const int cc = lane & 15;
  sb1[lane] = bh1[lane];   sb1[lane + 64] = bh1[lane + 64];
  sb2v[lane] = bh2[lane];  sb2v[lane + 64] = bh2[lane + 64];
  __syncthreads();
  int rofs[4];
#pragma unroll
  for (int rt = 0; rt < 4; ++rt) rofs[rt] = min(n0 + rt * 16 + (lane & 15), N - 1) * 128;
  const f32x4 vzero = {0.f, 0.f, 0.f, 0.f};
  f32x4 acc[4][8];
  ZERO_ACC;
  // layer 1, K=256: kt 0..3 from hidden, kt 4..7 from mi
  GEMM_GBL(hidden, rofs, 0, OFF_WH1_HI, OFF_WH1_LO, 0);
  GEMM_GBL(mi, rofs, 0, OFF_WH1_HI, OFF_WH1_LO, 4);
#pragma unroll
  for (int rt = 0; rt < 4; ++rt)
#pragma unroll
    for (int nt = 0; nt < 8; ++nt) {
      float bv = sb1[nt * 16 + cc];
#pragma unroll
      for (int reg = 0; reg < 4; ++reg) {
        int row = rt * 16 + ((lane >> 4) << 2) + reg;
        Xs[xidx(row, nt * 16 + cc)] = ftanh(acc[rt][nt][reg] + bv);
      }
    }
  // layer 2
  ZERO_ACC;
  GEMM_LDS(Xs, OFF_WH2_HI, OFF_WH2_LO);
#pragma unroll
  for (int rt = 0; rt < 4; ++rt)
#pragma unroll
    for (int nt = 0; nt < 8; ++nt) {
      float bv = sb2v[nt * 16 + cc];
#pragma unroll
      for (int reg = 0; reg < 4; ++reg) {
        int row = rt * 16 + ((lane >> 4) << 2) + reg;
        Xs[xidx(row, nt * 16 + cc)] = acc[rt][nt][reg] + bv;
      }
    }
  __syncthreads();
#pragma unroll 4
  for (int i = 0; i < 32; ++i) {
    int f = i * 64 + lane, row = f >> 5, c4 = f & 31;
    int gr = n0 + row;
    if (gr < N) {
      f32x4 v = *(const f32x4*)&Xs[xidx(row, c4 * 4)];
      f32x4 h = *(const f32x4*)&hidden[(size_t)gr * 128 + c4 * 4];
      *(f32x4*)&hidden_out[(size_t)gr * 128 + c4 * 4] = v + h;
    }
  }
}

extern "C" void kernel_launch(void* const* d_in, const int* in_sizes, int n_in,
                              void* d_out, int out_size, void* d_ws, size_t ws_size,
                              hipStream_t stream) {
  const float* coords = (const float*)d_in[0];
  const float* hidden = (const float*)d_in[1];
  const int* edges = (const int*)d_in[2];
  const float* W1 = (const float*)d_in[3];
  const float* b1 = (const float*)d_in[4];
  const float* W2 = (const float*)d_in[5];
  const float* b2 = (const float*)d_in[6];
  const float* Wa = (const float*)d_in[7];
  const float* ba = (const float*)d_in[8];
  const float* Wc1 = (const float*)d_in[9];
  const float* bc1 = (const float*)d_in[10];
  const float* Wc2 = (const float*)d_in[11];
  const float* Wh1 = (const float*)d_in[12];
  const float* bh1 = (const float*)d_in[13];
  const float* Wh2 = (const float*)d_in[14];
  const float* bh2 = (const float*)d_in[15];

  const int N = in_sizes[0] / 3;   // 30000
  const int E = in_sizes[2] / 2;   // 480000

  float* T = (float*)d_ws;                          // [N,128]
  float* mi = T + (size_t)N * 128;                  // [N,128]
  float* coords_out = (float*)d_out;                // [N,3]
  float* hidden_out = coords_out + (size_t)N * 3;   // [N,128]

  wconv_kernel<<<64, 256, 0, stream>>>(W1, 4, OFF_W1A_HI, OFF_W1A_LO);
  wconv_kernel<<<64, 256, 0, stream>>>(W1 + 128 * 128, 4, OFF_W1B_HI, OFF_W1B_LO);
  wconv_kernel<<<64, 256, 0, stream>>>(W2, 4, OFF_W2_HI, OFF_W2_LO);
  wconv_kernel<<<64, 256, 0, stream>>>(Wc1, 4, OFF_WC1_HI, OFF_WC1_LO);
  wconv_kernel<<<128, 256, 0, stream>>>(Wh1, 8, OFF_WH1_HI, OFF_WH1_LO);
  wconv_kernel<<<64, 256, 0, stream>>>(Wh2, 4, OFF_WH2_HI, OFF_WH2_LO);

  const int nb = (N + 63) / 64;
  tdst_kernel<<<nb, 64, 0, stream>>>(hidden, b1, T, N);
  edge_kernel<<<E / 64, 64, 0, stream>>>(coords, hidden, edges, W1, Wa, ba, b2, bc1,
                                         Wc2, T, mi, coords_out, E);
  node_kernel<<<nb, 64, 0, stream>>>(hidden, mi, bh1, bh2, hidden_out, N);
}

// Round 3
// 501.654 us; speedup vs baseline: 3.3897x; 1.5168x over previous
//
#include <hip/hip_runtime.h>
#include <hip/hip_bf16.h>
#include <math.h>

// EGNN layer, bf16-MFMA design v3 (latency-focused rework of R2):
//  - hconv: hidden -> global bf16 hi/lo planes (Hh,Hl). No per-GEMM cvt VALU.
//  - wconv: one launch builds all B-fragment planes in g_frags:
//      W1A,W1B,Wh1: hi+lo, natural k-order   (A operands are O(1) -> keep split)
//      W2,Wc1,Wh2 : hi only, PERMUTED k-order (see below)
//  - tdst: T = hidden@W1B + b1 (fp32, per-node, reused by 16 in-edges)
//  - edge: 3 GEMM layers + gate/coord epilogues, 1 wave = 64 edges = 4 dst nodes
//  - node: h = tanh([hidden|mi]@Wh1+bh1)@Wh2+bh2; residual add
// k-permutation trick: epilogue lane owns cols {nt*16+cl}; storing them at
// s = cl*8+nt makes each row's 8 values contiguous -> one ds_write_b128.
// Readers consume s-order directly; weight planes for LDS-sourced GEMMs are
// built with rows W[orig(s)], orig(s) = (s&7)*16 + (s>>3). Dot products are
// K-order invariant, so results are identical.
// LDS 19.8KB -> 8 blocks/CU (2 waves/SIMD) with __launch_bounds__(64,2).

typedef __attribute__((ext_vector_type(8))) short short8;
typedef __attribute__((ext_vector_type(4))) float f32x4;
typedef __attribute__((ext_vector_type(4))) unsigned int u32x4;

#define MFMA __builtin_amdgcn_mfma_f32_16x16x32_bf16

// u16-unit offsets into g_frags (each kt-chunk = 4096 u16)
#define OFF_W1A_HI 0
#define OFF_W1A_LO 16384
#define OFF_W1B_HI 32768
#define OFF_W1B_LO 49152
#define OFF_W2_HI  65536
#define OFF_WC1_HI 81920
#define OFF_WH1_HI 98304
#define OFF_WH1_LO 131072
#define OFF_WH2_HI 163840
#define FRAG_TOTAL 180224

__device__ __align__(16) unsigned short g_frags[FRAG_TOTAL];

#define DEVFN static __device__ __forceinline__

DEVFN unsigned short f2bf(float x) {  // fp32 -> bf16 RNE
  unsigned int u = __float_as_uint(x);
  u += 0x7fffu + ((u >> 16) & 1u);
  return (unsigned short)(u >> 16);
}
DEVFN float bf2f(unsigned short h) { return __uint_as_float(((unsigned int)h) << 16); }

DEVFN unsigned int pk2(float a, float b) {  // 2xf32 -> packed bf16x2 (cvt_pk)
  __hip_bfloat162 p = __float22bfloat162_rn(make_float2(a, b));
  union { __hip_bfloat162 h; unsigned int u; } cv;
  cv.h = p;
  return cv.u;
}

DEVFN float ftanh(float x) {  // tanh = 1 - 2/(e^{2x}+1)
  float e = exp2f(x * 2.8853900817779268f);
  return 1.0f - 2.0f * __builtin_amdgcn_rcpf(e + 1.0f);
}
DEVFN float fsigmoid(float x) {
  float e = exp2f(-x * 1.4426950408889634f);
  return __builtin_amdgcn_rcpf(1.0f + e);
}

DEVFN short8 bfrag(int off_u16, int kt, int nt, int lane) {
  return *(const short8*)(g_frags + off_u16 + (((kt << 3) + nt) << 9) + (lane << 3));
}

// swizzled bf16 LDS tile: row-major [64][128] u16, byte ^= ((row&7)<<4)
DEVFN short8 xs_read(const unsigned short* Xs, int row, int sbyte) {
  return *(const short8*)((const char*)Xs + row * 256 + (sbyte ^ ((row & 7) << 4)));
}
DEVFN void xs_write8(unsigned short* Xs, int row, int cl, const float* v) {
  u32x4 w;
  w[0] = pk2(v[0], v[1]); w[1] = pk2(v[2], v[3]);
  w[2] = pk2(v[4], v[5]); w[3] = pk2(v[6], v[7]);
  *(u32x4*)((char*)Xs + row * 256 + ((cl << 4) ^ ((row & 7) << 4))) = w;
}

#define ZERO_ACC                                                       \
  _Pragma("unroll") for (int rt = 0; rt < 4; ++rt)                     \
  _Pragma("unroll") for (int nt = 0; nt < 8; ++nt) acc[rt][nt] = vzero;

// ---------------- hconv: hidden -> bf16 hi/lo planes ----------------
__global__ __launch_bounds__(256) void hconv_kernel(const float* __restrict__ h,
                                                    unsigned short* __restrict__ Hh,
                                                    unsigned short* __restrict__ Hl,
                                                    int n4) {
  int i = blockIdx.x * 256 + threadIdx.x;
  if (i >= n4) return;
  f32x4 v = ((const f32x4*)h)[i];
  unsigned short hh[4], ll[4];
#pragma unroll
  for (int j = 0; j < 4; ++j) {
    hh[j] = f2bf(v[j]);
    ll[j] = f2bf(v[j] - bf2f(hh[j]));
  }
  ((uint2*)Hh)[i] = make_uint2(hh[0] | ((unsigned)hh[1] << 16), hh[2] | ((unsigned)hh[3] << 16));
  ((uint2*)Hl)[i] = make_uint2(ll[0] | ((unsigned)ll[1] << 16), ll[2] | ((unsigned)ll[3] << 16));
}

// ---------------- wconv: all weight planes, one launch ----------------
__global__ __launch_bounds__(256) void wconv_kernel(const float* __restrict__ W1,
                                                    const float* __restrict__ W2,
                                                    const float* __restrict__ Wc1,
                                                    const float* __restrict__ Wh1,
                                                    const float* __restrict__ Wh2) {
  int t = blockIdx.x * 256 + threadIdx.x;
  if (t >= 28 * 4096) return;
  int seg = t >> 12, r = t & 4095;
  int j = r & 7, lane = (r >> 3) & 63, nt = (r >> 9) & 7;
  int kg = lane >> 4, cl = lane & 15;
  const float* src; int kt, offH, offL, perm;
  if (seg < 4)       { src = W1;             kt = seg;      offH = OFF_W1A_HI; offL = OFF_W1A_LO; perm = 0; }
  else if (seg < 8)  { src = W1 + 128 * 128; kt = seg - 4;  offH = OFF_W1B_HI; offL = OFF_W1B_LO; perm = 0; }
  else if (seg < 12) { src = W2;             kt = seg - 8;  offH = OFF_W2_HI;  offL = -1;         perm = 1; }
  else if (seg < 16) { src = Wc1;            kt = seg - 12; offH = OFF_WC1_HI; offL = -1;         perm = 1; }
  else if (seg < 24) { src = Wh1;            kt = seg - 16; offH = OFF_WH1_HI; offL = OFF_WH1_LO; perm = 0; }
  else               { src = Wh2;            kt = seg - 24; offH = OFF_WH2_HI; offL = -1;         perm = 1; }
  int ke = kt * 32 + kg * 8 + j;                       // effective k index
  int k = perm ? ((ke & 7) * 16 + (ke >> 3)) : ke;     // source row in W
  float w = src[k * 128 + nt * 16 + cl];
  unsigned short h = f2bf(w);
  int fi = kt * 4096 + nt * 512 + lane * 8 + j;
  g_frags[offH + fi] = h;
  if (offL >= 0) g_frags[offL + fi] = f2bf(w - bf2f(h));
}

// ---------------- tdst: T = hidden @ W1B + b1 (fp32 out) ----------------
__global__ __launch_bounds__(64, 2) void tdst_kernel(const unsigned short* __restrict__ Hh,
                                                     const unsigned short* __restrict__ Hl,
                                                     const float* __restrict__ b1,
                                                     float* __restrict__ T, int N) {
  __shared__ float sb[128];
  const int lane = threadIdx.x, cl = lane & 15, kg = lane >> 4;
  const int n0 = blockIdx.x * 64;
  sb[lane] = b1[lane]; sb[lane + 64] = b1[lane + 64];
  int rows[4];
#pragma unroll
  for (int rt = 0; rt < 4; ++rt) rows[rt] = min(n0 + rt * 16 + cl, N - 1) << 7;
  const f32x4 vzero = {0.f, 0.f, 0.f, 0.f};
  f32x4 acc[4][8];
  ZERO_ACC;
#pragma unroll
  for (int ks = 0; ks < 4; ++ks) {
    short8 ah[4], al[4];
#pragma unroll
    for (int rt = 0; rt < 4; ++rt) {
      ah[rt] = *(const short8*)(Hh + rows[rt] + ks * 32 + kg * 8);
      al[rt] = *(const short8*)(Hl + rows[rt] + ks * 32 + kg * 8);
    }
#pragma unroll
    for (int nt = 0; nt < 8; ++nt) {
      short8 bh = bfrag(OFF_W1B_HI, ks, nt, lane);
      short8 bl = bfrag(OFF_W1B_LO, ks, nt, lane);
#pragma unroll
      for (int rt = 0; rt < 4; ++rt) {
        acc[rt][nt] = MFMA(ah[rt], bh, acc[rt][nt], 0, 0, 0);
        acc[rt][nt] = MFMA(al[rt], bh, acc[rt][nt], 0, 0, 0);
        acc[rt][nt] = MFMA(ah[rt], bl, acc[rt][nt], 0, 0, 0);
      }
    }
  }
#pragma unroll
  for (int rt = 0; rt < 4; ++rt)
#pragma unroll
    for (int nt = 0; nt < 8; ++nt) {
      float bv = sb[nt * 16 + cl];
#pragma unroll
      for (int reg = 0; reg < 4; ++reg) {
        int row = n0 + rt * 16 + kg * 4 + reg;
        if (row < N) T[(size_t)row * 128 + nt * 16 + cl] = acc[rt][nt][reg] + bv;
      }
    }
}

// ---------------- edge kernel: 64 edges (= 4 dst nodes) per wave ----------------
__global__ __launch_bounds__(64, 2) void edge_kernel(
    const float* __restrict__ coords, const int* __restrict__ edges,
    const float* __restrict__ W1, const float* __restrict__ b2,
    const float* __restrict__ Wa, const float* __restrict__ ba,
    const float* __restrict__ bc1, const float* __restrict__ Wc2,
    const float* __restrict__ T, const unsigned short* __restrict__ Hh,
    const unsigned short* __restrict__ Hl, unsigned short* __restrict__ Mh,
    unsigned short* __restrict__ Ml, float* __restrict__ coords_out, int E) {
  __shared__ __align__(16) unsigned short Xs[64 * 128];   // 16384 B
  __shared__ __align__(16) float sT[4 * 128];             // 2048 B
  __shared__ float sb2f[128], sbc1f[128];                 // 1024 B
  __shared__ unsigned short swl2h[128], swah[128], swc2h[128];  // 768 B

  const int lane = threadIdx.x, cl = lane & 15, kg = lane >> 4;
  const int e = blockIdx.x * 64 + lane;
  const int src = edges[e], dst = edges[E + e];

  const float cx = coords[3 * dst], cy = coords[3 * dst + 1], cz = coords[3 * dst + 2];
  const float dx = coords[3 * src] - cx, dy = coords[3 * src + 1] - cy, dz = coords[3 * src + 2] - cz;
  const float l2 = sqrtf(dx * dx + dy * dy + dz * dz);

  const float* Wl2 = W1 + 256 * 128;
  swl2h[lane] = f2bf(Wl2[lane]);  swl2h[lane + 64] = f2bf(Wl2[lane + 64]);
  swah[lane] = f2bf(Wa[lane]);    swah[lane + 64] = f2bf(Wa[lane + 64]);
  swc2h[lane] = f2bf(Wc2[lane]);  swc2h[lane + 64] = f2bf(Wc2[lane + 64]);
  sb2f[lane] = b2[lane];          sb2f[lane + 64] = b2[lane + 64];
  sbc1f[lane] = bc1[lane];        sbc1f[lane + 64] = bc1[lane + 64];
  const float ba_s = ba[0];

  int dstn[4], srcRow[4];
#pragma unroll
  for (int rt = 0; rt < 4; ++rt) dstn[rt] = __shfl(dst, rt << 4);
#pragma unroll
  for (int rt = 0; rt < 4; ++rt) srcRow[rt] = __shfl(src, (rt << 4) + cl) << 7;

  {  // stage T rows of this block's 4 dst nodes
    int drow = __shfl(dst, kg << 4);
    const float* Tp = T + (size_t)drow * 128 + cl * 8;
    *(f32x4*)&sT[kg * 128 + cl * 8] = *(const f32x4*)Tp;
    *(f32x4*)&sT[kg * 128 + cl * 8 + 4] = *(const f32x4*)(Tp + 4);
  }

  const f32x4 vzero = {0.f, 0.f, 0.f, 0.f};
  f32x4 acc[4][8];
  ZERO_ACC;

  // ---- layer 1: hsrc @ W1A (A hi/lo from planes, B hi/lo) ----
#pragma unroll
  for (int ks = 0; ks < 4; ++ks) {
    short8 ah[4], al[4];
#pragma unroll
    for (int rt = 0; rt < 4; ++rt) {
      ah[rt] = *(const short8*)(Hh + srcRow[rt] + ks * 32 + kg * 8);
      al[rt] = *(const short8*)(Hl + srcRow[rt] + ks * 32 + kg * 8);
    }
#pragma unroll
    for (int nt = 0; nt < 8; ++nt) {
      short8 bh = bfrag(OFF_W1A_HI, ks, nt, lane);
      short8 bl = bfrag(OFF_W1A_LO, ks, nt, lane);
#pragma unroll
      for (int rt = 0; rt < 4; ++rt) {
        acc[rt][nt] = MFMA(ah[rt], bh, acc[rt][nt], 0, 0, 0);
        acc[rt][nt] = MFMA(al[rt], bh, acc[rt][nt], 0, 0, 0);
        acc[rt][nt] = MFMA(ah[rt], bl, acc[rt][nt], 0, 0, 0);
      }
    }
  }

  // ---- epi 1: m1 = tanh(acc + T[dst] + l2*wl2) -> Xs (bf16, s-layout) ----
#pragma unroll
  for (int rt = 0; rt < 4; ++rt) {
    float l2r[4];
#pragma unroll
    for (int reg = 0; reg < 4; ++reg) l2r[reg] = __shfl(l2, rt * 16 + kg * 4 + reg);
    float vv[4][8];
#pragma unroll
    for (int nt = 0; nt < 8; ++nt) {
      float tv = sT[rt * 128 + nt * 16 + cl];
      float wl = bf2f(swl2h[nt * 16 + cl]);
#pragma unroll
      for (int reg = 0; reg < 4; ++reg)
        vv[reg][nt] = ftanh(acc[rt][nt][reg] + tv + l2r[reg] * wl);
    }
#pragma unroll
    for (int reg = 0; reg < 4; ++reg) xs_write8(Xs, rt * 16 + kg * 4 + reg, cl, vv[reg]);
  }

  // ---- layer 2: m1 @ W2 (A bf16 from LDS, B hi) ----
  ZERO_ACC;
  {
    short8 a[4][4];
#pragma unroll
    for (int rt = 0; rt < 4; ++rt)
#pragma unroll
      for (int ks = 0; ks < 4; ++ks)
        a[rt][ks] = xs_read(Xs, rt * 16 + cl, ks * 64 + kg * 16);
#pragma unroll
    for (int nt = 0; nt < 8; ++nt) {
      short8 b[4];
#pragma unroll
      for (int ks = 0; ks < 4; ++ks) b[ks] = bfrag(OFF_W2_HI, ks, nt, lane);
#pragma unroll
      for (int ks = 0; ks < 4; ++ks)
#pragma unroll
        for (int rt = 0; rt < 4; ++rt)
          acc[rt][nt] = MFMA(a[rt][ks], b[ks], acc[rt][nt], 0, 0, 0);
    }
  }

  // ---- epi 2: tanh+bias, attention gate, m_i sums, gated m -> Xs ----
  {
    float wac[8], b2c[8];
#pragma unroll
    for (int nt = 0; nt < 8; ++nt) {
      wac[nt] = bf2f(swah[nt * 16 + cl]);
      b2c[nt] = sb2f[nt * 16 + cl];
    }
#pragma unroll
    for (int rt = 0; rt < 4; ++rt)
#pragma unroll
      for (int nt = 0; nt < 8; ++nt)
#pragma unroll
        for (int reg = 0; reg < 4; ++reg)
          acc[rt][nt][reg] = ftanh(acc[rt][nt][reg] + b2c[nt]);
    float p[4][4];
#pragma unroll
    for (int rt = 0; rt < 4; ++rt)
#pragma unroll
      for (int reg = 0; reg < 4; ++reg) {
        float s = 0.f;
#pragma unroll
        for (int nt = 0; nt < 8; ++nt) s = fmaf(acc[rt][nt][reg], wac[nt], s);
        p[rt][reg] = s;
      }
#pragma unroll
    for (int m = 1; m <= 8; m <<= 1)
#pragma unroll
      for (int rt = 0; rt < 4; ++rt)
#pragma unroll
        for (int reg = 0; reg < 4; ++reg) p[rt][reg] += __shfl_xor(p[rt][reg], m);
#pragma unroll
    for (int rt = 0; rt < 4; ++rt)
#pragma unroll
      for (int reg = 0; reg < 4; ++reg) {
        float gg = fsigmoid(p[rt][reg] + ba_s);
#pragma unroll
        for (int nt = 0; nt < 8; ++nt) acc[rt][nt][reg] *= gg;
      }
    float cs[4][8];
#pragma unroll
    for (int rt = 0; rt < 4; ++rt)
#pragma unroll
      for (int nt = 0; nt < 8; ++nt)
        cs[rt][nt] = (acc[rt][nt][0] + acc[rt][nt][1]) + (acc[rt][nt][2] + acc[rt][nt][3]);
#pragma unroll
    for (int rt = 0; rt < 4; ++rt)
#pragma unroll
      for (int nt = 0; nt < 8; ++nt) {
        cs[rt][nt] += __shfl_xor(cs[rt][nt], 16);
        cs[rt][nt] += __shfl_xor(cs[rt][nt], 32);
      }
    if (lane < 16) {
#pragma unroll
      for (int rt = 0; rt < 4; ++rt) {
        size_t base = (size_t)dstn[rt] * 128 + lane;
#pragma unroll
        for (int nt = 0; nt < 8; ++nt) {
          float s = cs[rt][nt];
          unsigned short hh = f2bf(s);
          Mh[base + nt * 16] = hh;
          Ml[base + nt * 16] = f2bf(s - bf2f(hh));
        }
      }
    }
#pragma unroll
    for (int rt = 0; rt < 4; ++rt) {
      float vv[4][8];
#pragma unroll
      for (int nt = 0; nt < 8; ++nt)
#pragma unroll
        for (int reg = 0; reg < 4; ++reg) vv[reg][nt] = acc[rt][nt][reg];
#pragma unroll
      for (int reg = 0; reg < 4; ++reg) xs_write8(Xs, rt * 16 + kg * 4 + reg, cl, vv[reg]);
    }
  }

  // ---- layer 3: m @ Wc1 (A bf16 from LDS, B hi) ----
  ZERO_ACC;
  {
    short8 a[4][4];
#pragma unroll
    for (int rt = 0; rt < 4; ++rt)
#pragma unroll
      for (int ks = 0; ks < 4; ++ks)
        a[rt][ks] = xs_read(Xs, rt * 16 + cl, ks * 64 + kg * 16);
#pragma unroll
    for (int nt = 0; nt < 8; ++nt) {
      short8 b[4];
#pragma unroll
      for (int ks = 0; ks < 4; ++ks) b[ks] = bfrag(OFF_WC1_HI, ks, nt, lane);
#pragma unroll
      for (int ks = 0; ks < 4; ++ks)
#pragma unroll
        for (int rt = 0; rt < 4; ++rt)
          acc[rt][nt] = MFMA(a[rt][ks], b[ks], acc[rt][nt], 0, 0, 0);
    }
  }

  // ---- epi 3: c2 = tanh(tanh(acc+bc1).Wc2); coords segment-sum ----
  {
    float wcc[8], bcc[8];
#pragma unroll
    for (int nt = 0; nt < 8; ++nt) {
      wcc[nt] = bf2f(swc2h[nt * 16 + cl]);
      bcc[nt] = sbc1f[nt * 16 + cl];
    }
    float p[4][4];
#pragma unroll
    for (int rt = 0; rt < 4; ++rt)
#pragma unroll
      for (int reg = 0; reg < 4; ++reg) {
        float s = 0.f;
#pragma unroll
        for (int nt = 0; nt < 8; ++nt)
          s = fmaf(ftanh(acc[rt][nt][reg] + bcc[nt]), wcc[nt], s);
        p[rt][reg] = s;
      }
#pragma unroll
    for (int m = 1; m <= 8; m <<= 1)
#pragma unroll
      for (int rt = 0; rt < 4; ++rt)
#pragma unroll
        for (int reg = 0; reg < 4; ++reg) p[rt][reg] += __shfl_xor(p[rt][reg], m);
    float st[4];
#pragma unroll
    for (int rt = 0; rt < 4; ++rt) {
      float s = 0.f;
#pragma unroll
      for (int reg = 0; reg < 4; ++reg) {
        int sl = rt * 16 + kg * 4 + reg;
        float vx = __shfl(dx, sl), vy = __shfl(dy, sl), vz = __shfl(dz, sl);
        float cmp = ((cl & 3) == 1) ? vy : (((cl & 3) == 2) ? vz : vx);
        s = fmaf(cmp, ftanh(p[rt][reg]), s);
      }
      st[rt] = s;
    }
#pragma unroll
    for (int rt = 0; rt < 4; ++rt) {
      st[rt] += __shfl_xor(st[rt], 16);
      st[rt] += __shfl_xor(st[rt], 32);
    }
    if (lane < 3) {
#pragma unroll
      for (int rt = 0; rt < 4; ++rt)
        coords_out[dstn[rt] * 3 + lane] = coords[dstn[rt] * 3 + lane] + st[rt] * 0.0625f;
    }
  }
}

// ---------------- node kernel ----------------
__global__ __launch_bounds__(64, 2) void node_kernel(
    const float* __restrict__ hidden, const unsigned short* __restrict__ Hh,
    const unsigned short* __restrict__ Hl, const unsigned short* __restrict__ Mh,
    const unsigned short* __restrict__ Ml, const float* __restrict__ bh1,
    const float* __restrict__ bh2, float* __restrict__ hidden_out, int N) {
  __shared__ __align__(16) unsigned short Xs[64 * 128];
  __shared__ float sb1[128], sb2[128];
  const int lane = threadIdx.x, cl = lane & 15, kg = lane >> 4;
  const int n0 = blockIdx.x * 64;
  sb1[lane] = bh1[lane]; sb1[lane + 64] = bh1[lane + 64];
  sb2[lane] = bh2[lane]; sb2[lane + 64] = bh2[lane + 64];
  int rows[4];
#pragma unroll
  for (int rt = 0; rt < 4; ++rt) rows[rt] = min(n0 + rt * 16 + cl, N - 1) << 7;
  const f32x4 vzero = {0.f, 0.f, 0.f, 0.f};
  f32x4 acc[4][8];
  ZERO_ACC;
  // layer 1 (K=256): kt 0..3 hidden planes, kt 4..7 mi planes
#pragma unroll
  for (int half = 0; half < 2; ++half) {
    const unsigned short* Ph = half ? Mh : Hh;
    const unsigned short* Pl = half ? Ml : Hl;
#pragma unroll
    for (int ks = 0; ks < 4; ++ks) {
      short8 ah[4], al[4];
#pragma unroll
      for (int rt = 0; rt < 4; ++rt) {
        ah[rt] = *(const short8*)(Ph + rows[rt] + ks * 32 + kg * 8);
        al[rt] = *(const short8*)(Pl + rows[rt] + ks * 32 + kg * 8);
      }
#pragma unroll
      for (int nt = 0; nt < 8; ++nt) {
        short8 bh = bfrag(OFF_WH1_HI, half * 4 + ks, nt, lane);
        short8 bl = bfrag(OFF_WH1_LO, half * 4 + ks, nt, lane);
#pragma unroll
        for (int rt = 0; rt < 4; ++rt) {
          acc[rt][nt] = MFMA(ah[rt], bh, acc[rt][nt], 0, 0, 0);
          acc[rt][nt] = MFMA(al[rt], bh, acc[rt][nt], 0, 0, 0);
          acc[rt][nt] = MFMA(ah[rt], bl, acc[rt][nt], 0, 0, 0);
        }
      }
    }
  }
  // epi 1: h1 = tanh(acc + bh1) -> Xs
#pragma unroll
  for (int rt = 0; rt < 4; ++rt) {
    float vv[4][8];
#pragma unroll
    for (int nt = 0; nt < 8; ++nt) {
      float bv = sb1[nt * 16 + cl];
#pragma unroll
      for (int reg = 0; reg < 4; ++reg) vv[reg][nt] = ftanh(acc[rt][nt][reg] + bv);
    }
#pragma unroll
    for (int reg = 0; reg < 4; ++reg) xs_write8(Xs, rt * 16 + kg * 4 + reg, cl, vv[reg]);
  }
  // layer 2: h1 @ Wh2
  ZERO_ACC;
  {
    short8 a[4][4];
#pragma unroll
    for (int rt = 0; rt < 4; ++rt)
#pragma unroll
      for (int ks = 0; ks < 4; ++ks)
        a[rt][ks] = xs_read(Xs, rt * 16 + cl, ks * 64 + kg * 16);
#pragma unroll
    for (int nt = 0; nt < 8; ++nt) {
      short8 b[4];
#pragma unroll
      for (int ks = 0; ks < 4; ++ks) b[ks] = bfrag(OFF_WH2_HI, ks, nt, lane);
#pragma unroll
      for (int ks = 0; ks < 4; ++ks)
#pragma unroll
        for (int rt = 0; rt < 4; ++rt)
          acc[rt][nt] = MFMA(a[rt][ks], b[ks], acc[rt][nt], 0, 0, 0);
    }
  }
  // epi 2: hidden_out = hidden + acc + bh2
#pragma unroll
  for (int rt = 0; rt < 4; ++rt)
#pragma unroll
    for (int nt = 0; nt < 8; ++nt) {
      float bv = sb2[nt * 16 + cl];
#pragma unroll
      for (int reg = 0; reg < 4; ++reg) {
        int row = n0 + rt * 16 + kg * 4 + reg;
        if (row < N) {
          size_t o = (size_t)row * 128 + nt * 16 + cl;
          hidden_out[o] = hidden[o] + acc[rt][nt][reg] + bv;
        }
      }
    }
}

extern "C" void kernel_launch(void* const* d_in, const int* in_sizes, int n_in,
                              void* d_out, int out_size, void* d_ws, size_t ws_size,
                              hipStream_t stream) {
  const float* coords = (const float*)d_in[0];
  const float* hidden = (const float*)d_in[1];
  const int* edges = (const int*)d_in[2];
  const float* W1 = (const float*)d_in[3];
  const float* b1 = (const float*)d_in[4];
  const float* W2 = (const float*)d_in[5];
  const float* b2 = (const float*)d_in[6];
  const float* Wa = (const float*)d_in[7];
  const float* ba = (const float*)d_in[8];
  const float* Wc1 = (const float*)d_in[9];
  const float* bc1 = (const float*)d_in[10];
  const float* Wc2 = (const float*)d_in[11];
  const float* Wh1 = (const float*)d_in[12];
  const float* bh1 = (const float*)d_in[13];
  const float* Wh2 = (const float*)d_in[14];
  const float* bh2 = (const float*)d_in[15];

  const int N = in_sizes[0] / 3;   // 30000
  const int E = in_sizes[2] / 2;   // 480000

  float* T = (float*)d_ws;                                    // [N,128] f32
  unsigned short* Hh = (unsigned short*)(T + (size_t)N * 128);
  unsigned short* Hl = Hh + (size_t)N * 128;
  unsigned short* Mh = Hl + (size_t)N * 128;
  unsigned short* Ml = Mh + (size_t)N * 128;
  float* coords_out = (float*)d_out;                          // [N,3]
  float* hidden_out = coords_out + (size_t)N * 3;             // [N,128]

  const int n4 = N * 32;  // N*128/4
  hconv_kernel<<<(n4 + 255) / 256, 256, 0, stream>>>(hidden, Hh, Hl, n4);
  wconv_kernel<<<448, 256, 0, stream>>>(W1, W2, Wc1, Wh1, Wh2);
  const int nb = (N + 63) / 64;
  tdst_kernel<<<nb, 64, 0, stream>>>(Hh, Hl, b1, T, N);
  edge_kernel<<<E / 64, 64, 0, stream>>>(coords, edges, W1, b2, Wa, ba, bc1, Wc2,
                                         T, Hh, Hl, Mh, Ml, coords_out, E);
  node_kernel<<<nb, 64, 0, stream>>>(hidden, Hh, Hl, Mh, Ml, bh1, bh2, hidden_out, N);
}

// Round 4
// 342.365 us; speedup vs baseline: 4.9668x; 1.4653x over previous
//
#include <hip/hip_runtime.h>
#include <hip/hip_bf16.h>
#include <math.h>

// EGNN layer, bf16-MFMA v4 (R3 + spill fix + small-kernel parallelism):
//  - edge_kernel pinned to amdgpu_waves_per_eu(2,2): VGPR budget 256 (acc=128
//    must stay in-register; R3's allocator targeted 4 waves -> 128 VGPRs ->
//    ~94MB scratch writes per dispatch, the dominant stall).
//  - layers 2/3 restructured ks-outer (A-frag live range 16 regs, not 64).
//  - tdst/node: M=16 rows/wave (acc 32 VGPRs, Xs 4KB) -> 1875 blocks, high
//    occupancy for the latency-bound tails.
//  - numerics identical to R3 (absmax 0.03125 passed).
// Layout notes (unchanged): g_frags holds MFMA B-planes; W2/Wc1/Wh2 are
// hi-only in PERMUTED k-order matching the epilogue's s=cl*8+nt LDS layout
// (K-permutation leaves dot products invariant); W1A/W1B/Wh1 hi+lo natural.
// Xs swizzle: byte ^= ((row&7)<<4) -> conflict-free ds_read_b128/write_b128.

typedef __attribute__((ext_vector_type(8))) short short8;
typedef __attribute__((ext_vector_type(4))) float f32x4;
typedef __attribute__((ext_vector_type(4))) unsigned int u32x4;

#define MFMA __builtin_amdgcn_mfma_f32_16x16x32_bf16

// u16-unit offsets into g_frags (each kt-chunk = 4096 u16)
#define OFF_W1A_HI 0
#define OFF_W1A_LO 16384
#define OFF_W1B_HI 32768
#define OFF_W1B_LO 49152
#define OFF_W2_HI  65536
#define OFF_WC1_HI 81920
#define OFF_WH1_HI 98304
#define OFF_WH1_LO 131072
#define OFF_WH2_HI 163840
#define FRAG_TOTAL 180224

__device__ __align__(16) unsigned short g_frags[FRAG_TOTAL];

#define DEVFN static __device__ __forceinline__

DEVFN unsigned short f2bf(float x) {  // fp32 -> bf16 RNE
  unsigned int u = __float_as_uint(x);
  u += 0x7fffu + ((u >> 16) & 1u);
  return (unsigned short)(u >> 16);
}
DEVFN float bf2f(unsigned short h) { return __uint_as_float(((unsigned int)h) << 16); }

DEVFN unsigned int pk2(float a, float b) {  // 2xf32 -> packed bf16x2
  __hip_bfloat162 p = __float22bfloat162_rn(make_float2(a, b));
  union { __hip_bfloat162 h; unsigned int u; } cv;
  cv.h = p;
  return cv.u;
}

DEVFN float ftanh(float x) {  // tanh = 1 - 2/(e^{2x}+1)
  float e = exp2f(x * 2.8853900817779268f);
  return 1.0f - 2.0f * __builtin_amdgcn_rcpf(e + 1.0f);
}
DEVFN float fsigmoid(float x) {
  float e = exp2f(-x * 1.4426950408889634f);
  return __builtin_amdgcn_rcpf(1.0f + e);
}

DEVFN short8 bfrag(int off_u16, int kt, int nt, int lane) {
  return *(const short8*)(g_frags + off_u16 + (((kt << 3) + nt) << 9) + (lane << 3));
}

// swizzled bf16 LDS tile: row-major [R][128] u16, byte ^= ((row&7)<<4)
DEVFN short8 xs_read(const unsigned short* Xs, int row, int sbyte) {
  return *(const short8*)((const char*)Xs + row * 256 + (sbyte ^ ((row & 7) << 4)));
}
DEVFN void xs_write8(unsigned short* Xs, int row, int cl, const float* v) {
  u32x4 w;
  w[0] = pk2(v[0], v[1]); w[1] = pk2(v[2], v[3]);
  w[2] = pk2(v[4], v[5]); w[3] = pk2(v[6], v[7]);
  *(u32x4*)((char*)Xs + row * 256 + ((cl << 4) ^ ((row & 7) << 4))) = w;
}

#define ZERO_ACC4                                                      \
  _Pragma("unroll") for (int rt = 0; rt < 4; ++rt)                     \
  _Pragma("unroll") for (int nt = 0; nt < 8; ++nt) acc[rt][nt] = vzero;
#define ZERO_ACC1                                                      \
  _Pragma("unroll") for (int nt = 0; nt < 8; ++nt) acc[nt] = vzero;

// ---------------- hconv: hidden -> bf16 hi/lo planes ----------------
__global__ __launch_bounds__(256) void hconv_kernel(const float* __restrict__ h,
                                                    unsigned short* __restrict__ Hh,
                                                    unsigned short* __restrict__ Hl,
                                                    int n4) {
  int i = blockIdx.x * 256 + threadIdx.x;
  if (i >= n4) return;
  f32x4 v = ((const f32x4*)h)[i];
  unsigned short hh[4], ll[4];
#pragma unroll
  for (int j = 0; j < 4; ++j) {
    hh[j] = f2bf(v[j]);
    ll[j] = f2bf(v[j] - bf2f(hh[j]));
  }
  ((uint2*)Hh)[i] = make_uint2(hh[0] | ((unsigned)hh[1] << 16), hh[2] | ((unsigned)hh[3] << 16));
  ((uint2*)Hl)[i] = make_uint2(ll[0] | ((unsigned)ll[1] << 16), ll[2] | ((unsigned)ll[3] << 16));
}

// ---------------- wconv: all weight planes, one launch ----------------
__global__ __launch_bounds__(256) void wconv_kernel(const float* __restrict__ W1,
                                                    const float* __restrict__ W2,
                                                    const float* __restrict__ Wc1,
                                                    const float* __restrict__ Wh1,
                                                    const float* __restrict__ Wh2) {
  int t = blockIdx.x * 256 + threadIdx.x;
  if (t >= 28 * 4096) return;
  int seg = t >> 12, r = t & 4095;
  int j = r & 7, lane = (r >> 3) & 63, nt = (r >> 9) & 7;
  int kg = lane >> 4, cl = lane & 15;
  const float* src; int kt, offH, offL, perm;
  if (seg < 4)       { src = W1;             kt = seg;      offH = OFF_W1A_HI; offL = OFF_W1A_LO; perm = 0; }
  else if (seg < 8)  { src = W1 + 128 * 128; kt = seg - 4;  offH = OFF_W1B_HI; offL = OFF_W1B_LO; perm = 0; }
  else if (seg < 12) { src = W2;             kt = seg - 8;  offH = OFF_W2_HI;  offL = -1;         perm = 1; }
  else if (seg < 16) { src = Wc1;            kt = seg - 12; offH = OFF_WC1_HI; offL = -1;         perm = 1; }
  else if (seg < 24) { src = Wh1;            kt = seg - 16; offH = OFF_WH1_HI; offL = OFF_WH1_LO; perm = 0; }
  else               { src = Wh2;            kt = seg - 24; offH = OFF_WH2_HI; offL = -1;         perm = 1; }
  int ke = kt * 32 + kg * 8 + j;                       // effective k index
  int k = perm ? ((ke & 7) * 16 + (ke >> 3)) : ke;     // source row in W
  float w = src[k * 128 + nt * 16 + cl];
  unsigned short h = f2bf(w);
  int fi = kt * 4096 + nt * 512 + lane * 8 + j;
  g_frags[offH + fi] = h;
  if (offL >= 0) g_frags[offL + fi] = f2bf(w - bf2f(h));
}

// ---------------- tdst: T = hidden @ W1B + b1, M=16 rows/wave ----------------
__global__ __launch_bounds__(64) void tdst_kernel(const unsigned short* __restrict__ Hh,
                                                  const unsigned short* __restrict__ Hl,
                                                  const float* __restrict__ b1,
                                                  float* __restrict__ T, int N) {
  const int lane = threadIdx.x, cl = lane & 15, kg = lane >> 4;
  const int n0 = blockIdx.x * 16;
  const int row = min(n0 + cl, N - 1) << 7;
  const f32x4 vzero = {0.f, 0.f, 0.f, 0.f};
  f32x4 acc[8];
  ZERO_ACC1;
#pragma unroll
  for (int ks = 0; ks < 4; ++ks) {
    short8 ah = *(const short8*)(Hh + row + ks * 32 + kg * 8);
    short8 al = *(const short8*)(Hl + row + ks * 32 + kg * 8);
#pragma unroll
    for (int nt = 0; nt < 8; ++nt) {
      short8 bh = bfrag(OFF_W1B_HI, ks, nt, lane);
      short8 bl = bfrag(OFF_W1B_LO, ks, nt, lane);
      acc[nt] = MFMA(ah, bh, acc[nt], 0, 0, 0);
      acc[nt] = MFMA(al, bh, acc[nt], 0, 0, 0);
      acc[nt] = MFMA(ah, bl, acc[nt], 0, 0, 0);
    }
  }
#pragma unroll
  for (int nt = 0; nt < 8; ++nt) {
    float bv = b1[nt * 16 + cl];
#pragma unroll
    for (int reg = 0; reg < 4; ++reg) {
      int rw = n0 + kg * 4 + reg;
      if (rw < N) T[(size_t)rw * 128 + nt * 16 + cl] = acc[nt][reg] + bv;
    }
  }
}

// ---------------- edge kernel: 64 edges (= 4 dst nodes) per wave ----------------
__attribute__((amdgpu_waves_per_eu(2, 2)))
__global__ __launch_bounds__(64) void edge_kernel(
    const float* __restrict__ coords, const int* __restrict__ edges,
    const float* __restrict__ W1, const float* __restrict__ b2,
    const float* __restrict__ Wa, const float* __restrict__ ba,
    const float* __restrict__ bc1, const float* __restrict__ Wc2,
    const float* __restrict__ T, const unsigned short* __restrict__ Hh,
    const unsigned short* __restrict__ Hl, unsigned short* __restrict__ Mh,
    unsigned short* __restrict__ Ml, float* __restrict__ coords_out, int E) {
  __shared__ __align__(16) unsigned short Xs[64 * 128];   // 16384 B
  __shared__ __align__(16) float sT[4 * 128];             // 2048 B
  __shared__ float sb2f[128], sbc1f[128];                 // 1024 B
  __shared__ unsigned short swl2h[128], swah[128], swc2h[128];  // 768 B

  const int lane = threadIdx.x, cl = lane & 15, kg = lane >> 4;
  const int e = blockIdx.x * 64 + lane;
  const int src = edges[e], dst = edges[E + e];

  const float cx = coords[3 * dst], cy = coords[3 * dst + 1], cz = coords[3 * dst + 2];
  const float dx = coords[3 * src] - cx, dy = coords[3 * src + 1] - cy, dz = coords[3 * src + 2] - cz;
  const float l2 = sqrtf(dx * dx + dy * dy + dz * dz);

  const float* Wl2 = W1 + 256 * 128;
  swl2h[lane] = f2bf(Wl2[lane]);  swl2h[lane + 64] = f2bf(Wl2[lane + 64]);
  swah[lane] = f2bf(Wa[lane]);    swah[lane + 64] = f2bf(Wa[lane + 64]);
  swc2h[lane] = f2bf(Wc2[lane]);  swc2h[lane + 64] = f2bf(Wc2[lane + 64]);
  sb2f[lane] = b2[lane];          sb2f[lane + 64] = b2[lane + 64];
  sbc1f[lane] = bc1[lane];        sbc1f[lane + 64] = bc1[lane + 64];
  const float ba_s = ba[0];

  int dstn[4], srcRow[4];
#pragma unroll
  for (int rt = 0; rt < 4; ++rt) dstn[rt] = __shfl(dst, rt << 4);
#pragma unroll
  for (int rt = 0; rt < 4; ++rt) srcRow[rt] = __shfl(src, (rt << 4) + cl) << 7;

  {  // stage T rows of this block's 4 dst nodes
    int drow = __shfl(dst, kg << 4);
    const float* Tp = T + (size_t)drow * 128 + cl * 8;
    *(f32x4*)&sT[kg * 128 + cl * 8] = *(const f32x4*)Tp;
    *(f32x4*)&sT[kg * 128 + cl * 8 + 4] = *(const f32x4*)(Tp + 4);
  }

  const f32x4 vzero = {0.f, 0.f, 0.f, 0.f};
  f32x4 acc[4][8];
  ZERO_ACC4;

  // ---- layer 1: hsrc @ W1A (A hi/lo planes, B hi/lo) ----
#pragma unroll
  for (int ks = 0; ks < 4; ++ks) {
    short8 ah[4], al[4];
#pragma unroll
    for (int rt = 0; rt < 4; ++rt) {
      ah[rt] = *(const short8*)(Hh + srcRow[rt] + ks * 32 + kg * 8);
      al[rt] = *(const short8*)(Hl + srcRow[rt] + ks * 32 + kg * 8);
    }
#pragma unroll
    for (int nt = 0; nt < 8; ++nt) {
      short8 bh = bfrag(OFF_W1A_HI, ks, nt, lane);
      short8 bl = bfrag(OFF_W1A_LO, ks, nt, lane);
#pragma unroll
      for (int rt = 0; rt < 4; ++rt) {
        acc[rt][nt] = MFMA(ah[rt], bh, acc[rt][nt], 0, 0, 0);
        acc[rt][nt] = MFMA(al[rt], bh, acc[rt][nt], 0, 0, 0);
        acc[rt][nt] = MFMA(ah[rt], bl, acc[rt][nt], 0, 0, 0);
      }
    }
  }

  // ---- epi 1: m1 = tanh(acc + T[dst] + l2*wl2) -> Xs ----
#pragma unroll
  for (int rt = 0; rt < 4; ++rt) {
    float l2r[4];
#pragma unroll
    for (int reg = 0; reg < 4; ++reg) l2r[reg] = __shfl(l2, rt * 16 + kg * 4 + reg);
    float vv[4][8];
#pragma unroll
    for (int nt = 0; nt < 8; ++nt) {
      float tv = sT[rt * 128 + nt * 16 + cl];
      float wl = bf2f(swl2h[nt * 16 + cl]);
#pragma unroll
      for (int reg = 0; reg < 4; ++reg)
        vv[reg][nt] = ftanh(acc[rt][nt][reg] + tv + l2r[reg] * wl);
    }
#pragma unroll
    for (int reg = 0; reg < 4; ++reg) xs_write8(Xs, rt * 16 + kg * 4 + reg, cl, vv[reg]);
  }

  // ---- layer 2: m1 @ W2 (ks-outer; short A live range) ----
  ZERO_ACC4;
#pragma unroll
  for (int ks = 0; ks < 4; ++ks) {
    short8 a[4];
#pragma unroll
    for (int rt = 0; rt < 4; ++rt) a[rt] = xs_read(Xs, rt * 16 + cl, ks * 64 + kg * 16);
#pragma unroll
    for (int nt = 0; nt < 8; ++nt) {
      short8 b = bfrag(OFF_W2_HI, ks, nt, lane);
#pragma unroll
      for (int rt = 0; rt < 4; ++rt) acc[rt][nt] = MFMA(a[rt], b, acc[rt][nt], 0, 0, 0);
    }
  }

  // ---- epi 2: tanh+bias, gate, m_i sums, gated m -> Xs ----
  {
    float wac[8], b2c[8];
#pragma unroll
    for (int nt = 0; nt < 8; ++nt) {
      wac[nt] = bf2f(swah[nt * 16 + cl]);
      b2c[nt] = sb2f[nt * 16 + cl];
    }
#pragma unroll
    for (int rt = 0; rt < 4; ++rt)
#pragma unroll
      for (int nt = 0; nt < 8; ++nt)
#pragma unroll
        for (int reg = 0; reg < 4; ++reg)
          acc[rt][nt][reg] = ftanh(acc[rt][nt][reg] + b2c[nt]);
    float p[4][4];
#pragma unroll
    for (int rt = 0; rt < 4; ++rt)
#pragma unroll
      for (int reg = 0; reg < 4; ++reg) {
        float s = 0.f;
#pragma unroll
        for (int nt = 0; nt < 8; ++nt) s = fmaf(acc[rt][nt][reg], wac[nt], s);
        p[rt][reg] = s;
      }
#pragma unroll
    for (int m = 1; m <= 8; m <<= 1)
#pragma unroll
      for (int rt = 0; rt < 4; ++rt)
#pragma unroll
        for (int reg = 0; reg < 4; ++reg) p[rt][reg] += __shfl_xor(p[rt][reg], m);
#pragma unroll
    for (int rt = 0; rt < 4; ++rt)
#pragma unroll
      for (int reg = 0; reg < 4; ++reg) {
        float gg = fsigmoid(p[rt][reg] + ba_s);
#pragma unroll
        for (int nt = 0; nt < 8; ++nt) acc[rt][nt][reg] *= gg;
      }
    float cs[4][8];
#pragma unroll
    for (int rt = 0; rt < 4; ++rt)
#pragma unroll
      for (int nt = 0; nt < 8; ++nt)
        cs[rt][nt] = (acc[rt][nt][0] + acc[rt][nt][1]) + (acc[rt][nt][2] + acc[rt][nt][3]);
#pragma unroll
    for (int rt = 0; rt < 4; ++rt)
#pragma unroll
      for (int nt = 0; nt < 8; ++nt) {
        cs[rt][nt] += __shfl_xor(cs[rt][nt], 16);
        cs[rt][nt] += __shfl_xor(cs[rt][nt], 32);
      }
    if (lane < 16) {
#pragma unroll
      for (int rt = 0; rt < 4; ++rt) {
        size_t base = (size_t)dstn[rt] * 128 + lane;
#pragma unroll
        for (int nt = 0; nt < 8; ++nt) {
          float s = cs[rt][nt];
          unsigned short hh = f2bf(s);
          Mh[base + nt * 16] = hh;
          Ml[base + nt * 16] = f2bf(s - bf2f(hh));
        }
      }
    }
#pragma unroll
    for (int rt = 0; rt < 4; ++rt) {
      float vv[4][8];
#pragma unroll
      for (int nt = 0; nt < 8; ++nt)
#pragma unroll
        for (int reg = 0; reg < 4; ++reg) vv[reg][nt] = acc[rt][nt][reg];
#pragma unroll
      for (int reg = 0; reg < 4; ++reg) xs_write8(Xs, rt * 16 + kg * 4 + reg, cl, vv[reg]);
    }
  }

  // ---- layer 3: m @ Wc1 (ks-outer) ----
  ZERO_ACC4;
#pragma unroll
  for (int ks = 0; ks < 4; ++ks) {
    short8 a[4];
#pragma unroll
    for (int rt = 0; rt < 4; ++rt) a[rt] = xs_read(Xs, rt * 16 + cl, ks * 64 + kg * 16);
#pragma unroll
    for (int nt = 0; nt < 8; ++nt) {
      short8 b = bfrag(OFF_WC1_HI, ks, nt, lane);
#pragma unroll
      for (int rt = 0; rt < 4; ++rt) acc[rt][nt] = MFMA(a[rt], b, acc[rt][nt], 0, 0, 0);
    }
  }

  // ---- epi 3: c2 = tanh(tanh(acc+bc1).Wc2); coords segment-sum ----
  {
    float wcc[8], bcc[8];
#pragma unroll
    for (int nt = 0; nt < 8; ++nt) {
      wcc[nt] = bf2f(swc2h[nt * 16 + cl]);
      bcc[nt] = sbc1f[nt * 16 + cl];
    }
    float p[4][4];
#pragma unroll
    for (int rt = 0; rt < 4; ++rt)
#pragma unroll
      for (int reg = 0; reg < 4; ++reg) {
        float s = 0.f;
#pragma unroll
        for (int nt = 0; nt < 8; ++nt)
          s = fmaf(ftanh(acc[rt][nt][reg] + bcc[nt]), wcc[nt], s);
        p[rt][reg] = s;
      }
#pragma unroll
    for (int m = 1; m <= 8; m <<= 1)
#pragma unroll
      for (int rt = 0; rt < 4; ++rt)
#pragma unroll
        for (int reg = 0; reg < 4; ++reg) p[rt][reg] += __shfl_xor(p[rt][reg], m);
    float st[4];
#pragma unroll
    for (int rt = 0; rt < 4; ++rt) {
      float s = 0.f;
#pragma unroll
      for (int reg = 0; reg < 4; ++reg) {
        int sl = rt * 16 + kg * 4 + reg;
        float vx = __shfl(dx, sl), vy = __shfl(dy, sl), vz = __shfl(dz, sl);
        float cmp = ((cl & 3) == 1) ? vy : (((cl & 3) == 2) ? vz : vx);
        s = fmaf(cmp, ftanh(p[rt][reg]), s);
      }
      st[rt] = s;
    }
#pragma unroll
    for (int rt = 0; rt < 4; ++rt) {
      st[rt] += __shfl_xor(st[rt], 16);
      st[rt] += __shfl_xor(st[rt], 32);
    }
    if (lane < 3) {
#pragma unroll
      for (int rt = 0; rt < 4; ++rt)
        coords_out[dstn[rt] * 3 + lane] = coords[dstn[rt] * 3 + lane] + st[rt] * 0.0625f;
    }
  }
}

// ---------------- node kernel: M=16 rows/wave ----------------
__global__ __launch_bounds__(64) void node_kernel(
    const float* __restrict__ hidden, const unsigned short* __restrict__ Hh,
    const unsigned short* __restrict__ Hl, const unsigned short* __restrict__ Mh,
    const unsigned short* __restrict__ Ml, const float* __restrict__ bh1,
    const float* __restrict__ bh2, float* __restrict__ hidden_out, int N) {
  __shared__ __align__(16) unsigned short Xs[16 * 128];   // 4 KB
  const int lane = threadIdx.x, cl = lane & 15, kg = lane >> 4;
  const int n0 = blockIdx.x * 16;
  const int row = min(n0 + cl, N - 1) << 7;
  const f32x4 vzero = {0.f, 0.f, 0.f, 0.f};
  f32x4 acc[8];
  ZERO_ACC1;
  // layer 1 (K=256): kt 0..3 hidden planes, kt 4..7 mi planes
#pragma unroll
  for (int half = 0; half < 2; ++half) {
    const unsigned short* Ph = half ? Mh : Hh;
    const unsigned short* Pl = half ? Ml : Hl;
#pragma unroll
    for (int ks = 0; ks < 4; ++ks) {
      short8 ah = *(const short8*)(Ph + row + ks * 32 + kg * 8);
      short8 al = *(const short8*)(Pl + row + ks * 32 + kg * 8);
#pragma unroll
      for (int nt = 0; nt < 8; ++nt) {
        short8 bh = bfrag(OFF_WH1_HI, half * 4 + ks, nt, lane);
        short8 bl = bfrag(OFF_WH1_LO, half * 4 + ks, nt, lane);
        acc[nt] = MFMA(ah, bh, acc[nt], 0, 0, 0);
        acc[nt] = MFMA(al, bh, acc[nt], 0, 0, 0);
        acc[nt] = MFMA(ah, bl, acc[nt], 0, 0, 0);
      }
    }
  }
  // epi 1: h1 = tanh(acc + bh1) -> Xs
  {
    float vv[4][8];
#pragma unroll
    for (int nt = 0; nt < 8; ++nt) {
      float bv = bh1[nt * 16 + cl];
#pragma unroll
      for (int reg = 0; reg < 4; ++reg) vv[reg][nt] = ftanh(acc[nt][reg] + bv);
    }
#pragma unroll
    for (int reg = 0; reg < 4; ++reg) xs_write8(Xs, kg * 4 + reg, cl, vv[reg]);
  }
  __syncthreads();
  // layer 2: h1 @ Wh2
  ZERO_ACC1;
#pragma unroll
  for (int ks = 0; ks < 4; ++ks) {
    short8 a = xs_read(Xs, cl, ks * 64 + kg * 16);
#pragma unroll
    for (int nt = 0; nt < 8; ++nt) {
      short8 b = bfrag(OFF_WH2_HI, ks, nt, lane);
      acc[nt] = MFMA(a, b, acc[nt], 0, 0, 0);
    }
  }
  // epi 2: hidden_out = hidden + acc + bh2
#pragma unroll
  for (int nt = 0; nt < 8; ++nt) {
    float bv = bh2[nt * 16 + cl];
#pragma unroll
    for (int reg = 0; reg < 4; ++reg) {
      int rw = n0 + kg * 4 + reg;
      if (rw < N) {
        size_t o = (size_t)rw * 128 + nt * 16 + cl;
        hidden_out[o] = hidden[o] + acc[nt][reg] + bv;
      }
    }
  }
}

extern "C" void kernel_launch(void* const* d_in, const int* in_sizes, int n_in,
                              void* d_out, int out_size, void* d_ws, size_t ws_size,
                              hipStream_t stream) {
  const float* coords = (const float*)d_in[0];
  const float* hidden = (const float*)d_in[1];
  const int* edges = (const int*)d_in[2];
  const float* W1 = (const float*)d_in[3];
  const float* b1 = (const float*)d_in[4];
  const float* W2 = (const float*)d_in[5];
  const float* b2 = (const float*)d_in[6];
  const float* Wa = (const float*)d_in[7];
  const float* ba = (const float*)d_in[8];
  const float* Wc1 = (const float*)d_in[9];
  const float* bc1 = (const float*)d_in[10];
  const float* Wc2 = (const float*)d_in[11];
  const float* Wh1 = (const float*)d_in[12];
  const float* bh1 = (const float*)d_in[13];
  const float* Wh2 = (const float*)d_in[14];
  const float* bh2 = (const float*)d_in[15];

  const int N = in_sizes[0] / 3;   // 30000
  const int E = in_sizes[2] / 2;   // 480000

  float* T = (float*)d_ws;                                    // [N,128] f32
  unsigned short* Hh = (unsigned short*)(T + (size_t)N * 128);
  unsigned short* Hl = Hh + (size_t)N * 128;
  unsigned short* Mh = Hl + (size_t)N * 128;
  unsigned short* Ml = Mh + (size_t)N * 128;
  float* coords_out = (float*)d_out;                          // [N,3]
  float* hidden_out = coords_out + (size_t)N * 3;             // [N,128]

  const int n4 = N * 32;  // N*128/4
  hconv_kernel<<<(n4 + 255) / 256, 256, 0, stream>>>(hidden, Hh, Hl, n4);
  wconv_kernel<<<448, 256, 0, stream>>>(W1, W2, Wc1, Wh1, Wh2);
  const int nb16 = (N + 15) / 16;
  tdst_kernel<<<nb16, 64, 0, stream>>>(Hh, Hl, b1, T, N);
  edge_kernel<<<E / 64, 64, 0, stream>>>(coords, edges, W1, b2, Wa, ba, bc1, Wc2,
                                         T, Hh, Hl, Mh, Ml, coords_out, E);
  node_kernel<<<nb16, 64, 0, stream>>>(hidden, Hh, Hl, Mh, Ml, bh1, bh2, hidden_out, N);
}

// Round 5
// 307.322 us; speedup vs baseline: 5.5332x; 1.1140x over previous
//
#include <hip/hip_runtime.h>
#include <hip/hip_bf16.h>
#include <math.h>

// EGNN layer, bf16-MFMA v5 (spill-proof edge kernel):
//  R4 failed because the allocator ignored amdgpu_waves_per_eu and kept a
//  128-VGPR budget while the M=64 design needs ~180 live -> ~100MB scratch
//  round-trip per dispatch (WRITE_SIZE 116MB vs 16 ideal).
//  v5: edge kernel M=16 rows/wave (acc = 32 VGPRs, peak live ~90), 256-thread
//  blocks = 4 waves, one dst group (16 edges) per wave. All reductions
//  intra-wave; Xs is a wave-private 16-row slice (no barriers in main body).
//  tdst/node: same M=16/wave geometry at 256 threads/block (4x fewer blocks).
// Numerics identical to R3/R4 (absmax 0.03125 passed):
//  - hidden/m_i as bf16 hi+lo planes; W1A/W1B/Wh1 hi+lo; W2/Wc1/Wh2 hi-only.
//  - W2/Wc1/Wh2 planes in PERMUTED k-order matching the s=cl*8+nt epilogue
//    LDS layout (K-permutation leaves dot products invariant).
//  - Xs swizzle: byte ^= ((row&7)<<4).

typedef __attribute__((ext_vector_type(8))) short short8;
typedef __attribute__((ext_vector_type(4))) float f32x4;
typedef __attribute__((ext_vector_type(4))) unsigned int u32x4;

#define MFMA __builtin_amdgcn_mfma_f32_16x16x32_bf16

// u16-unit offsets into g_frags (each kt-chunk = 4096 u16)
#define OFF_W1A_HI 0
#define OFF_W1A_LO 16384
#define OFF_W1B_HI 32768
#define OFF_W1B_LO 49152
#define OFF_W2_HI  65536
#define OFF_WC1_HI 81920
#define OFF_WH1_HI 98304
#define OFF_WH1_LO 131072
#define OFF_WH2_HI 163840
#define FRAG_TOTAL 180224

__device__ __align__(16) unsigned short g_frags[FRAG_TOTAL];

#define DEVFN static __device__ __forceinline__

DEVFN unsigned short f2bf(float x) {  // fp32 -> bf16 RNE
  unsigned int u = __float_as_uint(x);
  u += 0x7fffu + ((u >> 16) & 1u);
  return (unsigned short)(u >> 16);
}
DEVFN float bf2f(unsigned short h) { return __uint_as_float(((unsigned int)h) << 16); }

DEVFN unsigned int pk2(float a, float b) {
  __hip_bfloat162 p = __float22bfloat162_rn(make_float2(a, b));
  union { __hip_bfloat162 h; unsigned int u; } cv;
  cv.h = p;
  return cv.u;
}

DEVFN float ftanh(float x) {  // tanh = 1 - 2/(e^{2x}+1)
  float e = exp2f(x * 2.8853900817779268f);
  return 1.0f - 2.0f * __builtin_amdgcn_rcpf(e + 1.0f);
}
DEVFN float fsigmoid(float x) {
  float e = exp2f(-x * 1.4426950408889634f);
  return __builtin_amdgcn_rcpf(1.0f + e);
}

DEVFN short8 bfrag(int off_u16, int kt, int nt, int lane) {
  return *(const short8*)(g_frags + off_u16 + (((kt << 3) + nt) << 9) + (lane << 3));
}

// swizzled bf16 LDS tile: row-major [64][128] u16, byte ^= ((row&7)<<4)
DEVFN short8 xs_read(const unsigned short* Xs, int row, int sbyte) {
  return *(const short8*)((const char*)Xs + row * 256 + (sbyte ^ ((row & 7) << 4)));
}
DEVFN void xs_write8(unsigned short* Xs, int row, int cl, const float* v) {
  u32x4 w;
  w[0] = pk2(v[0], v[1]); w[1] = pk2(v[2], v[3]);
  w[2] = pk2(v[4], v[5]); w[3] = pk2(v[6], v[7]);
  *(u32x4*)((char*)Xs + row * 256 + ((cl << 4) ^ ((row & 7) << 4))) = w;
}

#define ZERO_ACC1                                                      \
  _Pragma("unroll") for (int nt = 0; nt < 8; ++nt) acc[nt] = vzero;

// ---------------- hconv: hidden -> bf16 hi/lo planes ----------------
__global__ __launch_bounds__(256) void hconv_kernel(const float* __restrict__ h,
                                                    unsigned short* __restrict__ Hh,
                                                    unsigned short* __restrict__ Hl,
                                                    int n4) {
  int i = blockIdx.x * 256 + threadIdx.x;
  if (i >= n4) return;
  f32x4 v = ((const f32x4*)h)[i];
  unsigned short hh[4], ll[4];
#pragma unroll
  for (int j = 0; j < 4; ++j) {
    hh[j] = f2bf(v[j]);
    ll[j] = f2bf(v[j] - bf2f(hh[j]));
  }
  ((uint2*)Hh)[i] = make_uint2(hh[0] | ((unsigned)hh[1] << 16), hh[2] | ((unsigned)hh[3] << 16));
  ((uint2*)Hl)[i] = make_uint2(ll[0] | ((unsigned)ll[1] << 16), ll[2] | ((unsigned)ll[3] << 16));
}

// ---------------- wconv: all weight planes, one launch ----------------
__global__ __launch_bounds__(256) void wconv_kernel(const float* __restrict__ W1,
                                                    const float* __restrict__ W2,
                                                    const float* __restrict__ Wc1,
                                                    const float* __restrict__ Wh1,
                                                    const float* __restrict__ Wh2) {
  int t = blockIdx.x * 256 + threadIdx.x;
  if (t >= 28 * 4096) return;
  int seg = t >> 12, r = t & 4095;
  int j = r & 7, lane = (r >> 3) & 63, nt = (r >> 9) & 7;
  int kg = lane >> 4, cl = lane & 15;
  const float* src; int kt, offH, offL, perm;
  if (seg < 4)       { src = W1;             kt = seg;      offH = OFF_W1A_HI; offL = OFF_W1A_LO; perm = 0; }
  else if (seg < 8)  { src = W1 + 128 * 128; kt = seg - 4;  offH = OFF_W1B_HI; offL = OFF_W1B_LO; perm = 0; }
  else if (seg < 12) { src = W2;             kt = seg - 8;  offH = OFF_W2_HI;  offL = -1;         perm = 1; }
  else if (seg < 16) { src = Wc1;            kt = seg - 12; offH = OFF_WC1_HI; offL = -1;         perm = 1; }
  else if (seg < 24) { src = Wh1;            kt = seg - 16; offH = OFF_WH1_HI; offL = OFF_WH1_LO; perm = 0; }
  else               { src = Wh2;            kt = seg - 24; offH = OFF_WH2_HI; offL = -1;         perm = 1; }
  int ke = kt * 32 + kg * 8 + j;
  int k = perm ? ((ke & 7) * 16 + (ke >> 3)) : ke;
  float w = src[k * 128 + nt * 16 + cl];
  unsigned short h = f2bf(w);
  int fi = kt * 4096 + nt * 512 + lane * 8 + j;
  g_frags[offH + fi] = h;
  if (offL >= 0) g_frags[offL + fi] = f2bf(w - bf2f(h));
}

// ---------------- tdst: T = hidden @ W1B + b1; 4 waves/block, M=16/wave ----------------
__global__ __launch_bounds__(256) void tdst_kernel(const unsigned short* __restrict__ Hh,
                                                   const unsigned short* __restrict__ Hl,
                                                   const float* __restrict__ b1,
                                                   float* __restrict__ T, int N) {
  const int tid = threadIdx.x, wid = tid >> 6, lane = tid & 63;
  const int cl = lane & 15, kg = lane >> 4;
  const int n0 = blockIdx.x * 64 + wid * 16;
  const int row = min(n0 + cl, N - 1) << 7;
  const f32x4 vzero = {0.f, 0.f, 0.f, 0.f};
  f32x4 acc[8];
  ZERO_ACC1;
#pragma unroll
  for (int ks = 0; ks < 4; ++ks) {
    short8 ah = *(const short8*)(Hh + row + ks * 32 + kg * 8);
    short8 al = *(const short8*)(Hl + row + ks * 32 + kg * 8);
#pragma unroll
    for (int nt = 0; nt < 8; ++nt) {
      short8 bh = bfrag(OFF_W1B_HI, ks, nt, lane);
      short8 bl = bfrag(OFF_W1B_LO, ks, nt, lane);
      acc[nt] = MFMA(ah, bh, acc[nt], 0, 0, 0);
      acc[nt] = MFMA(al, bh, acc[nt], 0, 0, 0);
      acc[nt] = MFMA(ah, bl, acc[nt], 0, 0, 0);
    }
  }
#pragma unroll
  for (int nt = 0; nt < 8; ++nt) {
    float bv = b1[nt * 16 + cl];
#pragma unroll
    for (int reg = 0; reg < 4; ++reg) {
      int rw = n0 + kg * 4 + reg;
      if (rw < N) T[(size_t)rw * 128 + nt * 16 + cl] = acc[nt][reg] + bv;
    }
  }
}

// ---------------- edge kernel: 256 thr = 4 waves; wave = 16 edges = 1 dst ----------------
__global__ __launch_bounds__(256) void edge_kernel(
    const float* __restrict__ coords, const int* __restrict__ edges,
    const float* __restrict__ W1, const float* __restrict__ b2,
    const float* __restrict__ Wa, const float* __restrict__ ba,
    const float* __restrict__ bc1, const float* __restrict__ Wc2,
    const float* __restrict__ T, const unsigned short* __restrict__ Hh,
    const unsigned short* __restrict__ Hl, unsigned short* __restrict__ Mh,
    unsigned short* __restrict__ Ml, float* __restrict__ coords_out, int E) {
  __shared__ __align__(16) unsigned short Xs[64 * 128];         // 16 KB, wave-private slices
  __shared__ float sb2f[128], sbc1f[128];                       // 1 KB
  __shared__ unsigned short swl2h[128], swah[128], swc2h[128];  // 768 B

  const int tid = threadIdx.x, wid = tid >> 6, lane = tid & 63;
  const int cl = lane & 15, kg = lane >> 4;
  const int xrow0 = wid * 16;
  const int e0 = blockIdx.x * 64 + wid * 16;     // 16 edges, one dst group

  if (tid < 128) {
    swl2h[tid] = f2bf(W1[256 * 128 + tid]);
    swah[tid] = f2bf(Wa[tid]);
    swc2h[tid] = f2bf(Wc2[tid]);
    sb2f[tid] = b2[tid];
    sbc1f[tid] = bc1[tid];
  }
  __syncthreads();

  const int dst = edges[E + e0];                 // wave-uniform
  const int src = edges[e0 + cl];                // row cl's source node
  const int srcRow = src << 7;
  const float cx = coords[3 * dst], cy = coords[3 * dst + 1], cz = coords[3 * dst + 2];
  const float dx = coords[3 * src] - cx, dy = coords[3 * src + 1] - cy, dz = coords[3 * src + 2] - cz;
  const float l2 = sqrtf(dx * dx + dy * dy + dz * dz);
  const float ba_s = ba[0];

  const f32x4 vzero = {0.f, 0.f, 0.f, 0.f};
  f32x4 acc[8];
  ZERO_ACC1;

  // ---- layer 1: hsrc @ W1A (A hi/lo planes, B hi/lo) ----
#pragma unroll
  for (int ks = 0; ks < 4; ++ks) {
    short8 ah = *(const short8*)(Hh + srcRow + ks * 32 + kg * 8);
    short8 al = *(const short8*)(Hl + srcRow + ks * 32 + kg * 8);
#pragma unroll
    for (int nt = 0; nt < 8; ++nt) {
      short8 bh = bfrag(OFF_W1A_HI, ks, nt, lane);
      short8 bl = bfrag(OFF_W1A_LO, ks, nt, lane);
      acc[nt] = MFMA(ah, bh, acc[nt], 0, 0, 0);
      acc[nt] = MFMA(al, bh, acc[nt], 0, 0, 0);
      acc[nt] = MFMA(ah, bl, acc[nt], 0, 0, 0);
    }
  }

  // ---- epi 1: m1 = tanh(acc + T[dst] + l2*wl2) -> Xs ----
  {
    const float* Trow = T + (size_t)dst * 128;
    float l2r[4];
#pragma unroll
    for (int reg = 0; reg < 4; ++reg) l2r[reg] = __shfl(l2, kg * 4 + reg);
    float vv[4][8];
#pragma unroll
    for (int nt = 0; nt < 8; ++nt) {
      float tv = Trow[nt * 16 + cl];
      float wl = bf2f(swl2h[nt * 16 + cl]);
#pragma unroll
      for (int reg = 0; reg < 4; ++reg)
        vv[reg][nt] = ftanh(acc[nt][reg] + tv + l2r[reg] * wl);
    }
#pragma unroll
    for (int reg = 0; reg < 4; ++reg) xs_write8(Xs, xrow0 + kg * 4 + reg, cl, vv[reg]);
  }

  // ---- layer 2: m1 @ W2 (A from LDS, B hi) ----
  ZERO_ACC1;
#pragma unroll
  for (int ks = 0; ks < 4; ++ks) {
    short8 a = xs_read(Xs, xrow0 + cl, ks * 64 + kg * 16);
#pragma unroll
    for (int nt = 0; nt < 8; ++nt) {
      short8 b = bfrag(OFF_W2_HI, ks, nt, lane);
      acc[nt] = MFMA(a, b, acc[nt], 0, 0, 0);
    }
  }

  // ---- epi 2: tanh+bias, gate, m_i, gated m -> Xs ----
  {
    float wac[8], b2c[8];
#pragma unroll
    for (int nt = 0; nt < 8; ++nt) {
      wac[nt] = bf2f(swah[nt * 16 + cl]);
      b2c[nt] = sb2f[nt * 16 + cl];
    }
#pragma unroll
    for (int nt = 0; nt < 8; ++nt)
#pragma unroll
      for (int reg = 0; reg < 4; ++reg)
        acc[nt][reg] = ftanh(acc[nt][reg] + b2c[nt]);
    float p[4];
#pragma unroll
    for (int reg = 0; reg < 4; ++reg) {
      float s = 0.f;
#pragma unroll
      for (int nt = 0; nt < 8; ++nt) s = fmaf(acc[nt][reg], wac[nt], s);
      p[reg] = s;
    }
#pragma unroll
    for (int m = 1; m <= 8; m <<= 1)
#pragma unroll
      for (int reg = 0; reg < 4; ++reg) p[reg] += __shfl_xor(p[reg], m);
    float g[4];
#pragma unroll
    for (int reg = 0; reg < 4; ++reg) g[reg] = fsigmoid(p[reg] + ba_s);
#pragma unroll
    for (int nt = 0; nt < 8; ++nt)
#pragma unroll
      for (int reg = 0; reg < 4; ++reg) acc[nt][reg] *= g[reg];
    float cs[8];
#pragma unroll
    for (int nt = 0; nt < 8; ++nt) {
      cs[nt] = (acc[nt][0] + acc[nt][1]) + (acc[nt][2] + acc[nt][3]);
      cs[nt] += __shfl_xor(cs[nt], 16);
      cs[nt] += __shfl_xor(cs[nt], 32);
    }
    if (lane < 16) {
      size_t base = (size_t)dst * 128 + lane;
#pragma unroll
      for (int nt = 0; nt < 8; ++nt) {
        float s = cs[nt];
        unsigned short hh = f2bf(s);
        Mh[base + nt * 16] = hh;
        Ml[base + nt * 16] = f2bf(s - bf2f(hh));
      }
    }
    float vv[4][8];
#pragma unroll
    for (int nt = 0; nt < 8; ++nt)
#pragma unroll
      for (int reg = 0; reg < 4; ++reg) vv[reg][nt] = acc[nt][reg];
#pragma unroll
    for (int reg = 0; reg < 4; ++reg) xs_write8(Xs, xrow0 + kg * 4 + reg, cl, vv[reg]);
  }

  // ---- layer 3: m @ Wc1 (A from LDS, B hi) ----
  ZERO_ACC1;
#pragma unroll
  for (int ks = 0; ks < 4; ++ks) {
    short8 a = xs_read(Xs, xrow0 + cl, ks * 64 + kg * 16);
#pragma unroll
    for (int nt = 0; nt < 8; ++nt) {
      short8 b = bfrag(OFF_WC1_HI, ks, nt, lane);
      acc[nt] = MFMA(a, b, acc[nt], 0, 0, 0);
    }
  }

  // ---- epi 3: c2 = tanh(tanh(acc+bc1).Wc2); coords segment-sum ----
  {
    float wcc[8], bcc[8];
#pragma unroll
    for (int nt = 0; nt < 8; ++nt) {
      wcc[nt] = bf2f(swc2h[nt * 16 + cl]);
      bcc[nt] = sbc1f[nt * 16 + cl];
    }
    float p[4];
#pragma unroll
    for (int reg = 0; reg < 4; ++reg) {
      float s = 0.f;
#pragma unroll
      for (int nt = 0; nt < 8; ++nt)
        s = fmaf(ftanh(acc[nt][reg] + bcc[nt]), wcc[nt], s);
      p[reg] = s;
    }
#pragma unroll
    for (int m = 1; m <= 8; m <<= 1)
#pragma unroll
      for (int reg = 0; reg < 4; ++reg) p[reg] += __shfl_xor(p[reg], m);
    float st = 0.f;
#pragma unroll
    for (int reg = 0; reg < 4; ++reg) {
      int sl = kg * 4 + reg;
      float vx = __shfl(dx, sl), vy = __shfl(dy, sl), vz = __shfl(dz, sl);
      float cmp = ((cl & 3) == 1) ? vy : (((cl & 3) == 2) ? vz : vx);
      st = fmaf(cmp, ftanh(p[reg]), st);
    }
    st += __shfl_xor(st, 16);
    st += __shfl_xor(st, 32);
    if (lane < 3)
      coords_out[dst * 3 + lane] = coords[dst * 3 + lane] + st * 0.0625f;
  }
}

// ---------------- node kernel: 4 waves/block, M=16/wave ----------------
__global__ __launch_bounds__(256) void node_kernel(
    const float* __restrict__ hidden, const unsigned short* __restrict__ Hh,
    const unsigned short* __restrict__ Hl, const unsigned short* __restrict__ Mh,
    const unsigned short* __restrict__ Ml, const float* __restrict__ bh1,
    const float* __restrict__ bh2, float* __restrict__ hidden_out, int N) {
  __shared__ __align__(16) unsigned short Xs[64 * 128];  // wave-private 16-row slices
  const int tid = threadIdx.x, wid = tid >> 6, lane = tid & 63;
  const int cl = lane & 15, kg = lane >> 4;
  const int xrow0 = wid * 16;
  const int n0 = blockIdx.x * 64 + wid * 16;
  const int row = min(n0 + cl, N - 1) << 7;
  const f32x4 vzero = {0.f, 0.f, 0.f, 0.f};
  f32x4 acc[8];
  ZERO_ACC1;
#pragma unroll
  for (int half = 0; half < 2; ++half) {
    const unsigned short* Ph = half ? Mh : Hh;
    const unsigned short* Pl = half ? Ml : Hl;
#pragma unroll
    for (int ks = 0; ks < 4; ++ks) {
      short8 ah = *(const short8*)(Ph + row + ks * 32 + kg * 8);
      short8 al = *(const short8*)(Pl + row + ks * 32 + kg * 8);
#pragma unroll
      for (int nt = 0; nt < 8; ++nt) {
        short8 bh = bfrag(OFF_WH1_HI, half * 4 + ks, nt, lane);
        short8 bl = bfrag(OFF_WH1_LO, half * 4 + ks, nt, lane);
        acc[nt] = MFMA(ah, bh, acc[nt], 0, 0, 0);
        acc[nt] = MFMA(al, bh, acc[nt], 0, 0, 0);
        acc[nt] = MFMA(ah, bl, acc[nt], 0, 0, 0);
      }
    }
  }
  {
    float vv[4][8];
#pragma unroll
    for (int nt = 0; nt < 8; ++nt) {
      float bv = bh1[nt * 16 + cl];
#pragma unroll
      for (int reg = 0; reg < 4; ++reg) vv[reg][nt] = ftanh(acc[nt][reg] + bv);
    }
#pragma unroll
    for (int reg = 0; reg < 4; ++reg) xs_write8(Xs, xrow0 + kg * 4 + reg, cl, vv[reg]);
  }
  ZERO_ACC1;
#pragma unroll
  for (int ks = 0; ks < 4; ++ks) {
    short8 a = xs_read(Xs, xrow0 + cl, ks * 64 + kg * 16);
#pragma unroll
    for (int nt = 0; nt < 8; ++nt) {
      short8 b = bfrag(OFF_WH2_HI, ks, nt, lane);
      acc[nt] = MFMA(a, b, acc[nt], 0, 0, 0);
    }
  }
#pragma unroll
  for (int nt = 0; nt < 8; ++nt) {
    float bv = bh2[nt * 16 + cl];
#pragma unroll
    for (int reg = 0; reg < 4; ++reg) {
      int rw = n0 + kg * 4 + reg;
      if (rw < N) {
        size_t o = (size_t)rw * 128 + nt * 16 + cl;
        hidden_out[o] = hidden[o] + acc[nt][reg] + bv;
      }
    }
  }
}

extern "C" void kernel_launch(void* const* d_in, const int* in_sizes, int n_in,
                              void* d_out, int out_size, void* d_ws, size_t ws_size,
                              hipStream_t stream) {
  const float* coords = (const float*)d_in[0];
  const float* hidden = (const float*)d_in[1];
  const int* edges = (const int*)d_in[2];
  const float* W1 = (const float*)d_in[3];
  const float* b1 = (const float*)d_in[4];
  const float* W2 = (const float*)d_in[5];
  const float* b2 = (const float*)d_in[6];
  const float* Wa = (const float*)d_in[7];
  const float* ba = (const float*)d_in[8];
  const float* Wc1 = (const float*)d_in[9];
  const float* bc1 = (const float*)d_in[10];
  const float* Wc2 = (const float*)d_in[11];
  const float* Wh1 = (const float*)d_in[12];
  const float* bh1 = (const float*)d_in[13];
  const float* Wh2 = (const float*)d_in[14];
  const float* bh2 = (const float*)d_in[15];

  const int N = in_sizes[0] / 3;   // 30000
  const int E = in_sizes[2] / 2;   // 480000

  float* T = (float*)d_ws;                                    // [N,128] f32
  unsigned short* Hh = (unsigned short*)(T + (size_t)N * 128);
  unsigned short* Hl = Hh + (size_t)N * 128;
  unsigned short* Mh = Hl + (size_t)N * 128;
  unsigned short* Ml = Mh + (size_t)N * 128;
  float* coords_out = (float*)d_out;                          // [N,3]
  float* hidden_out = coords_out + (size_t)N * 3;             // [N,128]

  const int n4 = N * 32;  // N*128/4
  hconv_kernel<<<(n4 + 255) / 256, 256, 0, stream>>>(hidden, Hh, Hl, n4);
  wconv_kernel<<<448, 256, 0, stream>>>(W1, W2, Wc1, Wh1, Wh2);
  const int nb = (N + 63) / 64;
  tdst_kernel<<<nb, 256, 0, stream>>>(Hh, Hl, b1, T, N);
  edge_kernel<<<E / 64, 256, 0, stream>>>(coords, edges, W1, b2, Wa, ba, bc1, Wc2,
                                          T, Hh, Hl, Mh, Ml, coords_out, E);
  node_kernel<<<nb, 256, 0, stream>>>(hidden, Hh, Hl, Mh, Ml, bh1, bh2, hidden_out, N);
}

// Round 6
// 286.877 us; speedup vs baseline: 5.9275x; 1.0713x over previous
//
#include <hip/hip_runtime.h>
#include <hip/hip_bf16.h>
#include <math.h>

// EGNN layer, bf16-MFMA v6 (layer-1 hoist + VALU diet):
//  R5 counters: VALUBusy 59% vs MfmaUtil 18% -> edge kernel VALU-bound, and
//  60% of its MFMAs recomputed h_src@W1A per-EDGE (node-level quantity, 16x
//  redundant).
//  v6: st_kernel precomputes S[n]=hidden@W1A and T[n]=hidden@W1B+b1 per node;
//  edge layer1 = tanh(S[src]+T[dst]+l2*wl2) (reads only). Edge MFMA/wave
//  160->64. tanh/sigmoid use raw v_exp_f32/v_rcp_f32. st/node split the
//  8 nt-tiles across wave pairs (3750 waves, was 1875 -> better latency
//  hiding); node exchanges h1 halves via LDS with one barrier. hconv dropped
//  (in-register packed bf16 conversion). Workspace = 46MB, same as R5.
// Numerics identical to R5 (absmax 0.03125): hi+lo split for W1A/W1B/Wh1 and
// A-operands; W2/Wc1/Wh2 hi-only in PERMUTED k-order matching the s=cl*8+nt
// epilogue layout. Xs swizzle: byte ^= ((row&7)<<4).

typedef __attribute__((ext_vector_type(8))) short short8;
typedef __attribute__((ext_vector_type(4))) float f32x4;
typedef __attribute__((ext_vector_type(4))) unsigned int u32x4;

#define MFMA __builtin_amdgcn_mfma_f32_16x16x32_bf16

// u16-unit offsets into g_frags (each kt-chunk = 4096 u16)
#define OFF_W1A_HI 0
#define OFF_W1A_LO 16384
#define OFF_W1B_HI 32768
#define OFF_W1B_LO 49152
#define OFF_W2_HI  65536
#define OFF_WC1_HI 81920
#define OFF_WH1_HI 98304
#define OFF_WH1_LO 131072
#define OFF_WH2_HI 163840
#define FRAG_TOTAL 180224

__device__ __align__(16) unsigned short g_frags[FRAG_TOTAL];

#define DEVFN static __device__ __forceinline__

DEVFN unsigned short f2bf(float x) {  // fp32 -> bf16 RNE (bit path, for wconv)
  unsigned int u = __float_as_uint(x);
  u += 0x7fffu + ((u >> 16) & 1u);
  return (unsigned short)(u >> 16);
}
DEVFN float bf2f(unsigned short h) { return __uint_as_float(((unsigned int)h) << 16); }

DEVFN unsigned int pk2(float a, float b) {  // -> packed bf16x2 (a=low), RNE
  __hip_bfloat162 p = __float22bfloat162_rn(make_float2(a, b));
  union { __hip_bfloat162 h; unsigned int u; } cv;
  cv.h = p;
  return cv.u;
}

DEVFN float fexp2(float x) {  // 2^x, native
  float r;
  asm volatile("v_exp_f32 %0, %1" : "=v"(r) : "v"(x));
  return r;
}
DEVFN float frcp(float x) {
  float r;
  asm volatile("v_rcp_f32 %0, %1" : "=v"(r) : "v"(x));
  return r;
}
DEVFN float ftanh(float x) {  // 1 - 2/(e^{2x}+1); saturates at +/-1
  return 1.0f - 2.0f * frcp(fexp2(x * 2.8853900817779268f) + 1.0f);
}
DEVFN float fsigmoid(float x) {
  return frcp(1.0f + fexp2(-x * 1.4426950408889634f));
}

// 8 consecutive f32 -> bf16 hi/lo fragments (packed cvt pairs)
DEVFN void mk8(const float* __restrict__ x, short8& hi, short8& lo) {
  unsigned int hp[4], lp[4];
#pragma unroll
  for (int q = 0; q < 4; ++q) hp[q] = pk2(x[2 * q], x[2 * q + 1]);
#pragma unroll
  for (int q = 0; q < 4; ++q) {
    float f0 = __uint_as_float(hp[q] << 16);
    float f1 = __uint_as_float(hp[q] & 0xffff0000u);
    lp[q] = pk2(x[2 * q] - f0, x[2 * q + 1] - f1);
  }
  union { u32x4 u; short8 s; } ch, clo;
  ch.u[0] = hp[0]; ch.u[1] = hp[1]; ch.u[2] = hp[2]; ch.u[3] = hp[3];
  clo.u[0] = lp[0]; clo.u[1] = lp[1]; clo.u[2] = lp[2]; clo.u[3] = lp[3];
  hi = ch.s; lo = clo.s;
}

DEVFN short8 bfrag(int off_u16, int kt, int nt, int lane) {
  return *(const short8*)(g_frags + off_u16 + (((kt << 3) + nt) << 9) + (lane << 3));
}

// swizzled bf16 LDS tile: row-major [R][128] u16, byte ^= ((row&7)<<4)
DEVFN short8 xs_read(const unsigned short* Xs, int row, int sbyte) {
  return *(const short8*)((const char*)Xs + row * 256 + (sbyte ^ ((row & 7) << 4)));
}
DEVFN void xs_write8(unsigned short* Xs, int row, int cl, const float* v) {
  u32x4 w;
  w[0] = pk2(v[0], v[1]); w[1] = pk2(v[2], v[3]);
  w[2] = pk2(v[4], v[5]); w[3] = pk2(v[6], v[7]);
  *(u32x4*)((char*)Xs + row * 256 + ((cl << 4) ^ ((row & 7) << 4))) = w;
}
DEVFN void xs_write4(unsigned short* Xs, int row, int byte0, const float* v) {
  uint2 w;
  w.x = pk2(v[0], v[1]); w.y = pk2(v[2], v[3]);
  *(uint2*)((char*)Xs + row * 256 + (byte0 ^ ((row & 7) << 4))) = w;
}

#define ZERO8 { _Pragma("unroll") for (int nt = 0; nt < 8; ++nt) acc[nt] = vzero; }
#define ZERO4(a) { _Pragma("unroll") for (int q = 0; q < 4; ++q) (a)[q] = vzero; }

// ---------------- wconv: all weight planes, one launch ----------------
__global__ __launch_bounds__(256) void wconv_kernel(const float* __restrict__ W1,
                                                    const float* __restrict__ W2,
                                                    const float* __restrict__ Wc1,
                                                    const float* __restrict__ Wh1,
                                                    const float* __restrict__ Wh2) {
  int t = blockIdx.x * 256 + threadIdx.x;
  if (t >= 28 * 4096) return;
  int seg = t >> 12, r = t & 4095;
  int j = r & 7, lane = (r >> 3) & 63, nt = (r >> 9) & 7;
  int kg = lane >> 4, cl = lane & 15;
  const float* src; int kt, offH, offL, perm;
  if (seg < 4)       { src = W1;             kt = seg;      offH = OFF_W1A_HI; offL = OFF_W1A_LO; perm = 0; }
  else if (seg < 8)  { src = W1 + 128 * 128; kt = seg - 4;  offH = OFF_W1B_HI; offL = OFF_W1B_LO; perm = 0; }
  else if (seg < 12) { src = W2;             kt = seg - 8;  offH = OFF_W2_HI;  offL = -1;         perm = 1; }
  else if (seg < 16) { src = Wc1;            kt = seg - 12; offH = OFF_WC1_HI; offL = -1;         perm = 1; }
  else if (seg < 24) { src = Wh1;            kt = seg - 16; offH = OFF_WH1_HI; offL = OFF_WH1_LO; perm = 0; }
  else               { src = Wh2;            kt = seg - 24; offH = OFF_WH2_HI; offL = -1;         perm = 1; }
  int ke = kt * 32 + kg * 8 + j;
  int k = perm ? ((ke & 7) * 16 + (ke >> 3)) : ke;
  float w = src[k * 128 + nt * 16 + cl];
  unsigned short h = f2bf(w);
  int fi = kt * 4096 + nt * 512 + lane * 8 + j;
  g_frags[offH + fi] = h;
  if (offL >= 0) g_frags[offL + fi] = f2bf(w - bf2f(h));
}

// -------- st: S = hidden@W1A, T = hidden@W1B + b1; wave = 16 rows x 4 nt --------
__global__ __launch_bounds__(256) void st_kernel(const float* __restrict__ hidden,
                                                 const float* __restrict__ b1,
                                                 float* __restrict__ S,
                                                 float* __restrict__ T, int N) {
  const int tid = threadIdx.x, wid = tid >> 6, lane = tid & 63;
  const int cl = lane & 15, kg = lane >> 4;
  const int rg = wid >> 1, nh = wid & 1;          // row-group, nt-half
  const int n0 = blockIdx.x * 32 + rg * 16;
  const float* Arow = hidden + ((size_t)min(n0 + cl, N - 1) << 7);
  const f32x4 vzero = {0.f, 0.f, 0.f, 0.f};
  f32x4 accS[4], accT[4];
  ZERO4(accS); ZERO4(accT);
#pragma unroll
  for (int ks = 0; ks < 4; ++ks) {
    float x[8];
    *(f32x4*)&x[0] = *(const f32x4*)(Arow + ks * 32 + kg * 8);
    *(f32x4*)&x[4] = *(const f32x4*)(Arow + ks * 32 + kg * 8 + 4);
    short8 ah, al;
    mk8(x, ah, al);
#pragma unroll
    for (int q = 0; q < 4; ++q) {
      int nt = nh * 4 + q;
      short8 bh = bfrag(OFF_W1A_HI, ks, nt, lane);
      short8 bl = bfrag(OFF_W1A_LO, ks, nt, lane);
      accS[q] = MFMA(ah, bh, accS[q], 0, 0, 0);
      accS[q] = MFMA(al, bh, accS[q], 0, 0, 0);
      accS[q] = MFMA(ah, bl, accS[q], 0, 0, 0);
      bh = bfrag(OFF_W1B_HI, ks, nt, lane);
      bl = bfrag(OFF_W1B_LO, ks, nt, lane);
      accT[q] = MFMA(ah, bh, accT[q], 0, 0, 0);
      accT[q] = MFMA(al, bh, accT[q], 0, 0, 0);
      accT[q] = MFMA(ah, bl, accT[q], 0, 0, 0);
    }
  }
#pragma unroll
  for (int q = 0; q < 4; ++q) {
    int nt = nh * 4 + q;
    float bv = b1[nt * 16 + cl];
#pragma unroll
    for (int reg = 0; reg < 4; ++reg) {
      int rw = n0 + kg * 4 + reg;
      if (rw < N) {
        size_t o = (size_t)rw * 128 + nt * 16 + cl;
        S[o] = accS[q][reg];
        T[o] = accT[q][reg] + bv;
      }
    }
  }
}

// ------- edge: 256 thr = 4 waves; wave = 16 edges = 1 dst; no layer-1 GEMM -------
__global__ __launch_bounds__(256) void edge_kernel(
    const float* __restrict__ coords, const int* __restrict__ edges,
    const float* __restrict__ W1, const float* __restrict__ b2,
    const float* __restrict__ Wa, const float* __restrict__ ba,
    const float* __restrict__ bc1, const float* __restrict__ Wc2,
    const float* __restrict__ T, const float* __restrict__ S,
    unsigned short* __restrict__ Mh, unsigned short* __restrict__ Ml,
    float* __restrict__ coords_out, int E) {
  __shared__ __align__(16) unsigned short Xs[64 * 128];   // 16 KB, wave-private slices
  __shared__ float swl2f[128], swaf[128], swc2f[128], sb2f[128], sbc1f[128];  // 2.5 KB

  const int tid = threadIdx.x, wid = tid >> 6, lane = tid & 63;
  const int cl = lane & 15, kg = lane >> 4;
  const int xrow0 = wid * 16;
  const int e0 = blockIdx.x * 64 + wid * 16;     // 16 edges, one dst group

  if (tid < 128) {
    swl2f[tid] = W1[256 * 128 + tid];
    swaf[tid] = Wa[tid];
    swc2f[tid] = Wc2[tid];
    sb2f[tid] = b2[tid];
    sbc1f[tid] = bc1[tid];
  }
  __syncthreads();

  const int dst = edges[E + e0];                 // wave-uniform
  const int src = edges[e0 + cl];                // row cl's source node
  const float cx = coords[3 * dst], cy = coords[3 * dst + 1], cz = coords[3 * dst + 2];
  const float dx = coords[3 * src] - cx, dy = coords[3 * src + 1] - cy, dz = coords[3 * src + 2] - cz;
  const float l2 = sqrtf(dx * dx + dy * dy + dz * dz);
  const float ba_s = ba[0];

  const f32x4 vzero = {0.f, 0.f, 0.f, 0.f};
  f32x4 acc[8];

  // ---- epi 1 (no GEMM): m1 = tanh(S[src] + T[dst] + l2*wl2) -> Xs ----
  {
    const float* Trow = T + (size_t)dst * 128;
    const float* Srow[4];
    float l2r[4];
#pragma unroll
    for (int reg = 0; reg < 4; ++reg) {
      Srow[reg] = S + ((size_t)__shfl(src, kg * 4 + reg) << 7);
      l2r[reg] = __shfl(l2, kg * 4 + reg);
    }
    float vv[4][8];
#pragma unroll
    for (int nt = 0; nt < 8; ++nt) {
      const int c = nt * 16 + cl;
      float tv = Trow[c];
      float wl = swl2f[c];
#pragma unroll
      for (int reg = 0; reg < 4; ++reg)
        vv[reg][nt] = ftanh(Srow[reg][c] + tv + l2r[reg] * wl);
    }
#pragma unroll
    for (int reg = 0; reg < 4; ++reg) xs_write8(Xs, xrow0 + kg * 4 + reg, cl, vv[reg]);
  }

  // ---- layer 2: m1 @ W2 (A from LDS, B hi) ----
  ZERO8;
#pragma unroll
  for (int ks = 0; ks < 4; ++ks) {
    short8 a = xs_read(Xs, xrow0 + cl, ks * 64 + kg * 16);
#pragma unroll
    for (int nt = 0; nt < 8; ++nt) {
      short8 b = bfrag(OFF_W2_HI, ks, nt, lane);
      acc[nt] = MFMA(a, b, acc[nt], 0, 0, 0);
    }
  }

  // ---- epi 2: tanh+bias, gate, m_i, gated m -> Xs ----
  {
    float wac[8], b2c[8];
#pragma unroll
    for (int nt = 0; nt < 8; ++nt) {
      wac[nt] = swaf[nt * 16 + cl];
      b2c[nt] = sb2f[nt * 16 + cl];
    }
#pragma unroll
    for (int nt = 0; nt < 8; ++nt)
#pragma unroll
      for (int reg = 0; reg < 4; ++reg)
        acc[nt][reg] = ftanh(acc[nt][reg] + b2c[nt]);
    float p[4];
#pragma unroll
    for (int reg = 0; reg < 4; ++reg) {
      float s = 0.f;
#pragma unroll
      for (int nt = 0; nt < 8; ++nt) s = fmaf(acc[nt][reg], wac[nt], s);
      p[reg] = s;
    }
#pragma unroll
    for (int m = 1; m <= 8; m <<= 1)
#pragma unroll
      for (int reg = 0; reg < 4; ++reg) p[reg] += __shfl_xor(p[reg], m);
    float g[4];
#pragma unroll
    for (int reg = 0; reg < 4; ++reg) g[reg] = fsigmoid(p[reg] + ba_s);
#pragma unroll
    for (int nt = 0; nt < 8; ++nt)
#pragma unroll
      for (int reg = 0; reg < 4; ++reg) acc[nt][reg] *= g[reg];
    float cs[8];
#pragma unroll
    for (int nt = 0; nt < 8; ++nt) {
      cs[nt] = (acc[nt][0] + acc[nt][1]) + (acc[nt][2] + acc[nt][3]);
      cs[nt] += __shfl_xor(cs[nt], 16);
      cs[nt] += __shfl_xor(cs[nt], 32);
    }
    if (lane < 16) {
      size_t base = (size_t)dst * 128 + lane;
#pragma unroll
      for (int nt = 0; nt < 8; ++nt) {
        float s = cs[nt];
        unsigned short hh = f2bf(s);
        Mh[base + nt * 16] = hh;
        Ml[base + nt * 16] = f2bf(s - bf2f(hh));
      }
    }
    float vv[4][8];
#pragma unroll
    for (int nt = 0; nt < 8; ++nt)
#pragma unroll
      for (int reg = 0; reg < 4; ++reg) vv[reg][nt] = acc[nt][reg];
#pragma unroll
    for (int reg = 0; reg < 4; ++reg) xs_write8(Xs, xrow0 + kg * 4 + reg, cl, vv[reg]);
  }

  // ---- layer 3: m @ Wc1 (A from LDS, B hi) ----
  ZERO8;
#pragma unroll
  for (int ks = 0; ks < 4; ++ks) {
    short8 a = xs_read(Xs, xrow0 + cl, ks * 64 + kg * 16);
#pragma unroll
    for (int nt = 0; nt < 8; ++nt) {
      short8 b = bfrag(OFF_WC1_HI, ks, nt, lane);
      acc[nt] = MFMA(a, b, acc[nt], 0, 0, 0);
    }
  }

  // ---- epi 3: c2 = tanh(tanh(acc+bc1).Wc2); coords segment-sum ----
  {
    float wcc[8], bcc[8];
#pragma unroll
    for (int nt = 0; nt < 8; ++nt) {
      wcc[nt] = swc2f[nt * 16 + cl];
      bcc[nt] = sbc1f[nt * 16 + cl];
    }
    float p[4];
#pragma unroll
    for (int reg = 0; reg < 4; ++reg) {
      float s = 0.f;
#pragma unroll
      for (int nt = 0; nt < 8; ++nt)
        s = fmaf(ftanh(acc[nt][reg] + bcc[nt]), wcc[nt], s);
      p[reg] = s;
    }
#pragma unroll
    for (int m = 1; m <= 8; m <<= 1)
#pragma unroll
      for (int reg = 0; reg < 4; ++reg) p[reg] += __shfl_xor(p[reg], m);
    float st = 0.f;
#pragma unroll
    for (int reg = 0; reg < 4; ++reg) {
      int sl = kg * 4 + reg;
      float vx = __shfl(dx, sl), vy = __shfl(dy, sl), vz = __shfl(dz, sl);
      float cmp = ((cl & 3) == 1) ? vy : (((cl & 3) == 2) ? vz : vx);
      st = fmaf(cmp, ftanh(p[reg]), st);
    }
    st += __shfl_xor(st, 16);
    st += __shfl_xor(st, 32);
    if (lane < 3)
      coords_out[dst * 3 + lane] = coords[dst * 3 + lane] + st * 0.0625f;
  }
}

// ------- node: wave pair shares 16 rows, nt-halves; one barrier for h1 -------
__global__ __launch_bounds__(256) void node_kernel(
    const float* __restrict__ hidden, const unsigned short* __restrict__ Mh,
    const unsigned short* __restrict__ Ml, const float* __restrict__ bh1,
    const float* __restrict__ bh2, float* __restrict__ hidden_out, int N) {
  __shared__ __align__(16) unsigned short Xs[32 * 128];   // 8 KB: 2 row-groups
  const int tid = threadIdx.x, wid = tid >> 6, lane = tid & 63;
  const int cl = lane & 15, kg = lane >> 4;
  const int rg = wid >> 1, nh = wid & 1;
  const int n0 = blockIdx.x * 32 + rg * 16;
  const int rmin = min(n0 + cl, N - 1);
  const f32x4 vzero = {0.f, 0.f, 0.f, 0.f};
  f32x4 acc[4];
  ZERO4(acc);
  // layer 1 half 0: hidden (f32, convert in-register)
  {
    const float* Arow = hidden + ((size_t)rmin << 7);
#pragma unroll
    for (int ks = 0; ks < 4; ++ks) {
      float x[8];
      *(f32x4*)&x[0] = *(const f32x4*)(Arow + ks * 32 + kg * 8);
      *(f32x4*)&x[4] = *(const f32x4*)(Arow + ks * 32 + kg * 8 + 4);
      short8 ah, al;
      mk8(x, ah, al);
#pragma unroll
      for (int q = 0; q < 4; ++q) {
        int nt = nh * 4 + q;
        short8 bh = bfrag(OFF_WH1_HI, ks, nt, lane);
        short8 bl = bfrag(OFF_WH1_LO, ks, nt, lane);
        acc[q] = MFMA(ah, bh, acc[q], 0, 0, 0);
        acc[q] = MFMA(al, bh, acc[q], 0, 0, 0);
        acc[q] = MFMA(ah, bl, acc[q], 0, 0, 0);
      }
    }
  }
  // layer 1 half 1: m_i (bf16 hi/lo planes)
  {
    const int prow = rmin << 7;
#pragma unroll
    for (int ks = 0; ks < 4; ++ks) {
      short8 ah = *(const short8*)(Mh + prow + ks * 32 + kg * 8);
      short8 al = *(const short8*)(Ml + prow + ks * 32 + kg * 8);
#pragma unroll
      for (int q = 0; q < 4; ++q) {
        int nt = nh * 4 + q;
        short8 bh = bfrag(OFF_WH1_HI, 4 + ks, nt, lane);
        short8 bl = bfrag(OFF_WH1_LO, 4 + ks, nt, lane);
        acc[q] = MFMA(ah, bh, acc[q], 0, 0, 0);
        acc[q] = MFMA(al, bh, acc[q], 0, 0, 0);
        acc[q] = MFMA(ah, bl, acc[q], 0, 0, 0);
      }
    }
  }
  // epi 1: h1 = tanh(acc + bh1) -> Xs (this wave's 4-col half)
  {
    float vv[4][4];
#pragma unroll
    for (int q = 0; q < 4; ++q) {
      float bv = bh1[(nh * 4 + q) * 16 + cl];
#pragma unroll
      for (int reg = 0; reg < 4; ++reg) vv[reg][q] = ftanh(acc[q][reg] + bv);
    }
#pragma unroll
    for (int reg = 0; reg < 4; ++reg)
      xs_write4(Xs, rg * 16 + kg * 4 + reg, cl * 16 + nh * 8, vv[reg]);
  }
  __syncthreads();
  // layer 2: h1 @ Wh2 (full rows, this wave's nt-half)
  ZERO4(acc);
#pragma unroll
  for (int ks = 0; ks < 4; ++ks) {
    short8 a = xs_read(Xs, rg * 16 + cl, ks * 64 + kg * 16);
#pragma unroll
    for (int q = 0; q < 4; ++q) {
      short8 b = bfrag(OFF_WH2_HI, ks, nh * 4 + q, lane);
      acc[q] = MFMA(a, b, acc[q], 0, 0, 0);
    }
  }
  // epi 2: hidden_out = hidden + acc + bh2
#pragma unroll
  for (int q = 0; q < 4; ++q) {
    int nt = nh * 4 + q;
    float bv = bh2[nt * 16 + cl];
#pragma unroll
    for (int reg = 0; reg < 4; ++reg) {
      int rw = n0 + kg * 4 + reg;
      if (rw < N) {
        size_t o = (size_t)rw * 128 + nt * 16 + cl;
        hidden_out[o] = hidden[o] + acc[q][reg] + bv;
      }
    }
  }
}

extern "C" void kernel_launch(void* const* d_in, const int* in_sizes, int n_in,
                              void* d_out, int out_size, void* d_ws, size_t ws_size,
                              hipStream_t stream) {
  const float* coords = (const float*)d_in[0];
  const float* hidden = (const float*)d_in[1];
  const int* edges = (const int*)d_in[2];
  const float* W1 = (const float*)d_in[3];
  const float* b1 = (const float*)d_in[4];
  const float* W2 = (const float*)d_in[5];
  const float* b2 = (const float*)d_in[6];
  const float* Wa = (const float*)d_in[7];
  const float* ba = (const float*)d_in[8];
  const float* Wc1 = (const float*)d_in[9];
  const float* bc1 = (const float*)d_in[10];
  const float* Wc2 = (const float*)d_in[11];
  const float* Wh1 = (const float*)d_in[12];
  const float* bh1 = (const float*)d_in[13];
  const float* Wh2 = (const float*)d_in[14];
  const float* bh2 = (const float*)d_in[15];

  const int N = in_sizes[0] / 3;   // 30000
  const int E = in_sizes[2] / 2;   // 480000

  float* T = (float*)d_ws;                                    // [N,128] f32
  float* S = T + (size_t)N * 128;                             // [N,128] f32
  unsigned short* Mh = (unsigned short*)(S + (size_t)N * 128);
  unsigned short* Ml = Mh + (size_t)N * 128;
  float* coords_out = (float*)d_out;                          // [N,3]
  float* hidden_out = coords_out + (size_t)N * 3;             // [N,128]

  wconv_kernel<<<448, 256, 0, stream>>>(W1, W2, Wc1, Wh1, Wh2);
  const int nb32 = (N + 31) / 32;
  st_kernel<<<nb32, 256, 0, stream>>>(hidden, b1, S, T, N);
  edge_kernel<<<E / 64, 256, 0, stream>>>(coords, edges, W1, b2, Wa, ba, bc1, Wc2,
                                          T, S, Mh, Ml, coords_out, E);
  node_kernel<<<nb32, 256, 0, stream>>>(hidden, Mh, Ml, bh1, bh2, hidden_out, N);
}

// Round 7
// 256.318 us; speedup vs baseline: 6.6342x; 1.1192x over previous
//
#include <hip/hip_runtime.h>
#include <hip/hip_bf16.h>
#include <math.h>

// EGNN layer, bf16-MFMA v7 (epi1 vectorization + finer st/node waves):
//  R6 counters: edge VALUBusy 44% / MfmaUtil 8%, non-edge ~126us.
//  v7 changes:
//   - W2 plane switched to NATURAL k-order; edge epi1 re-assigned lane ->
//     (row=lane&15, 32 contiguous cols): S/T/wl2 become f32x4 vector loads
//     (was 40 scalar stride-16 loads/lane), zero shfl, 4x16B Xs writes.
//     Wc1/Wh2 keep the cl*8+nt perm (producers write from MFMA acc layout).
//     Bit-identical numerics (k-reorder leaves dot products invariant).
//   - st/node: nt split 4-way -> blocks of 16 rows x 4 waves (2 nt-tiles
//     each), grid 1875, 7500 waves (~7.3/SIMD) for latency hiding.
//   - m_i store distributed over all 64 lanes.
// Carried invariants: hi+lo split for W1A/W1B/Wh1 + A-operands; W2/Wc1/Wh2
// hi-only; Xs swizzle byte ^= ((row&7)<<4); edge wave = 16 edges = 1 dst.

typedef __attribute__((ext_vector_type(8))) short short8;
typedef __attribute__((ext_vector_type(4))) float f32x4;
typedef __attribute__((ext_vector_type(4))) unsigned int u32x4;

#define MFMA __builtin_amdgcn_mfma_f32_16x16x32_bf16

// u16-unit offsets into g_frags (each kt-chunk = 4096 u16)
#define OFF_W1A_HI 0
#define OFF_W1A_LO 16384
#define OFF_W1B_HI 32768
#define OFF_W1B_LO 49152
#define OFF_W2_HI  65536
#define OFF_WC1_HI 81920
#define OFF_WH1_HI 98304
#define OFF_WH1_LO 131072
#define OFF_WH2_HI 163840
#define FRAG_TOTAL 180224

__device__ __align__(16) unsigned short g_frags[FRAG_TOTAL];

#define DEVFN static __device__ __forceinline__

DEVFN unsigned short f2bf(float x) {  // fp32 -> bf16 RNE
  unsigned int u = __float_as_uint(x);
  u += 0x7fffu + ((u >> 16) & 1u);
  return (unsigned short)(u >> 16);
}
DEVFN float bf2f(unsigned short h) { return __uint_as_float(((unsigned int)h) << 16); }

DEVFN unsigned int pk2(float a, float b) {  // -> packed bf16x2 (a=low), RNE
  __hip_bfloat162 p = __float22bfloat162_rn(make_float2(a, b));
  union { __hip_bfloat162 h; unsigned int u; } cv;
  cv.h = p;
  return cv.u;
}

DEVFN float fexp2(float x) {
  float r;
  asm volatile("v_exp_f32 %0, %1" : "=v"(r) : "v"(x));
  return r;
}
DEVFN float frcp(float x) {
  float r;
  asm volatile("v_rcp_f32 %0, %1" : "=v"(r) : "v"(x));
  return r;
}
DEVFN float ftanh(float x) {  // 1 - 2/(e^{2x}+1); saturates at +/-1
  return 1.0f - 2.0f * frcp(fexp2(x * 2.8853900817779268f) + 1.0f);
}
DEVFN float fsigmoid(float x) {
  return frcp(1.0f + fexp2(-x * 1.4426950408889634f));
}

// 8 consecutive f32 -> bf16 hi/lo fragments (packed cvt pairs)
DEVFN void mk8(const float* __restrict__ x, short8& hi, short8& lo) {
  unsigned int hp[4], lp[4];
#pragma unroll
  for (int q = 0; q < 4; ++q) hp[q] = pk2(x[2 * q], x[2 * q + 1]);
#pragma unroll
  for (int q = 0; q < 4; ++q) {
    float f0 = __uint_as_float(hp[q] << 16);
    float f1 = __uint_as_float(hp[q] & 0xffff0000u);
    lp[q] = pk2(x[2 * q] - f0, x[2 * q + 1] - f1);
  }
  union { u32x4 u; short8 s; } ch, clo;
  ch.u[0] = hp[0]; ch.u[1] = hp[1]; ch.u[2] = hp[2]; ch.u[3] = hp[3];
  clo.u[0] = lp[0]; clo.u[1] = lp[1]; clo.u[2] = lp[2]; clo.u[3] = lp[3];
  hi = ch.s; lo = clo.s;
}

DEVFN short8 bfrag(int off_u16, int kt, int nt, int lane) {
  return *(const short8*)(g_frags + off_u16 + (((kt << 3) + nt) << 9) + (lane << 3));
}

// swizzled bf16 LDS tile: row-major [R][128] u16, byte ^= ((row&7)<<4)
DEVFN short8 xs_read(const unsigned short* Xs, int row, int sbyte) {
  return *(const short8*)((const char*)Xs + row * 256 + (sbyte ^ ((row & 7) << 4)));
}
DEVFN void xs_write8(unsigned short* Xs, int row, int cl, const float* v) {
  u32x4 w;
  w[0] = pk2(v[0], v[1]); w[1] = pk2(v[2], v[3]);
  w[2] = pk2(v[4], v[5]); w[3] = pk2(v[6], v[7]);
  *(u32x4*)((char*)Xs + row * 256 + ((cl << 4) ^ ((row & 7) << 4))) = w;
}

#define ZERO8 { _Pragma("unroll") for (int nt = 0; nt < 8; ++nt) acc[nt] = vzero; }
#define ZERO2(a) { _Pragma("unroll") for (int q = 0; q < 2; ++q) (a)[q] = vzero; }

// ---------------- wconv: all weight planes, one launch ----------------
__global__ __launch_bounds__(256) void wconv_kernel(const float* __restrict__ W1,
                                                    const float* __restrict__ W2,
                                                    const float* __restrict__ Wc1,
                                                    const float* __restrict__ Wh1,
                                                    const float* __restrict__ Wh2) {
  int t = blockIdx.x * 256 + threadIdx.x;
  if (t >= 28 * 4096) return;
  int seg = t >> 12, r = t & 4095;
  int j = r & 7, lane = (r >> 3) & 63, nt = (r >> 9) & 7;
  int kg = lane >> 4, cl = lane & 15;
  const float* src; int kt, offH, offL, perm;
  if (seg < 4)       { src = W1;             kt = seg;      offH = OFF_W1A_HI; offL = OFF_W1A_LO; perm = 0; }
  else if (seg < 8)  { src = W1 + 128 * 128; kt = seg - 4;  offH = OFF_W1B_HI; offL = OFF_W1B_LO; perm = 0; }
  else if (seg < 12) { src = W2;             kt = seg - 8;  offH = OFF_W2_HI;  offL = -1;         perm = 0; }  // natural now
  else if (seg < 16) { src = Wc1;            kt = seg - 12; offH = OFF_WC1_HI; offL = -1;         perm = 1; }
  else if (seg < 24) { src = Wh1;            kt = seg - 16; offH = OFF_WH1_HI; offL = OFF_WH1_LO; perm = 0; }
  else               { src = Wh2;            kt = seg - 24; offH = OFF_WH2_HI; offL = -1;         perm = 1; }
  int ke = kt * 32 + kg * 8 + j;
  int k = perm ? ((ke & 7) * 16 + (ke >> 3)) : ke;
  float w = src[k * 128 + nt * 16 + cl];
  unsigned short h = f2bf(w);
  int fi = kt * 4096 + nt * 512 + lane * 8 + j;
  g_frags[offH + fi] = h;
  if (offL >= 0) g_frags[offL + fi] = f2bf(w - bf2f(h));
}

// -------- st: S = hidden@W1A, T = hidden@W1B + b1; block = 16 rows x 4 waves --------
__global__ __launch_bounds__(256) void st_kernel(const float* __restrict__ hidden,
                                                 const float* __restrict__ b1,
                                                 float* __restrict__ S,
                                                 float* __restrict__ T, int N) {
  const int tid = threadIdx.x, wid = tid >> 6, lane = tid & 63;
  const int cl = lane & 15, kg = lane >> 4;
  const int n0 = blockIdx.x * 16;
  const float* Arow = hidden + ((size_t)min(n0 + cl, N - 1) << 7);
  const f32x4 vzero = {0.f, 0.f, 0.f, 0.f};
  f32x4 accS[2], accT[2];
  ZERO2(accS); ZERO2(accT);
#pragma unroll
  for (int ks = 0; ks < 4; ++ks) {
    float x[8];
    *(f32x4*)&x[0] = *(const f32x4*)(Arow + ks * 32 + kg * 8);
    *(f32x4*)&x[4] = *(const f32x4*)(Arow + ks * 32 + kg * 8 + 4);
    short8 ah, al;
    mk8(x, ah, al);
#pragma unroll
    for (int q = 0; q < 2; ++q) {
      int nt = wid * 2 + q;
      short8 bh = bfrag(OFF_W1A_HI, ks, nt, lane);
      short8 bl = bfrag(OFF_W1A_LO, ks, nt, lane);
      accS[q] = MFMA(ah, bh, accS[q], 0, 0, 0);
      accS[q] = MFMA(al, bh, accS[q], 0, 0, 0);
      accS[q] = MFMA(ah, bl, accS[q], 0, 0, 0);
      bh = bfrag(OFF_W1B_HI, ks, nt, lane);
      bl = bfrag(OFF_W1B_LO, ks, nt, lane);
      accT[q] = MFMA(ah, bh, accT[q], 0, 0, 0);
      accT[q] = MFMA(al, bh, accT[q], 0, 0, 0);
      accT[q] = MFMA(ah, bl, accT[q], 0, 0, 0);
    }
  }
#pragma unroll
  for (int q = 0; q < 2; ++q) {
    int nt = wid * 2 + q;
    float bv = b1[nt * 16 + cl];
#pragma unroll
    for (int reg = 0; reg < 4; ++reg) {
      int rw = n0 + kg * 4 + reg;
      if (rw < N) {
        size_t o = (size_t)rw * 128 + nt * 16 + cl;
        S[o] = accS[q][reg];
        T[o] = accT[q][reg] + bv;
      }
    }
  }
}

// ------- edge: 256 thr = 4 waves; wave = 16 edges = 1 dst -------
__global__ __launch_bounds__(256) void edge_kernel(
    const float* __restrict__ coords, const int* __restrict__ edges,
    const float* __restrict__ W1, const float* __restrict__ b2,
    const float* __restrict__ Wa, const float* __restrict__ ba,
    const float* __restrict__ bc1, const float* __restrict__ Wc2,
    const float* __restrict__ T, const float* __restrict__ S,
    unsigned short* __restrict__ Mh, unsigned short* __restrict__ Ml,
    float* __restrict__ coords_out, int E) {
  __shared__ __align__(16) unsigned short Xs[64 * 128];   // 16 KB, wave-private slices
  __shared__ __align__(16) float swl2f[128];
  __shared__ float swaf[128], swc2f[128], sb2f[128], sbc1f[128];  // 2.5 KB total

  const int tid = threadIdx.x, wid = tid >> 6, lane = tid & 63;
  const int cl = lane & 15, kg = lane >> 4;
  const int xrow0 = wid * 16;
  const int e0 = blockIdx.x * 64 + wid * 16;     // 16 edges, one dst group

  if (tid < 128) {
    swl2f[tid] = W1[256 * 128 + tid];
    swaf[tid] = Wa[tid];
    swc2f[tid] = Wc2[tid];
    sb2f[tid] = b2[tid];
    sbc1f[tid] = bc1[tid];
  }
  __syncthreads();

  const int dst = edges[E + e0];                 // wave-uniform
  const int src = edges[e0 + cl];                // row cl's source node
  const float cx = coords[3 * dst], cy = coords[3 * dst + 1], cz = coords[3 * dst + 2];
  const float dx = coords[3 * src] - cx, dy = coords[3 * src + 1] - cy, dz = coords[3 * src + 2] - cz;
  const float l2 = sqrtf(dx * dx + dy * dy + dz * dz);
  const float ba_s = ba[0];

  const f32x4 vzero = {0.f, 0.f, 0.f, 0.f};
  f32x4 acc[8];

  // ---- epi 1 (vectorized): m1 = tanh(S[src] + T[dst] + l2*wl2) -> Xs ----
  // lane -> (row = cl, cols cb*32..+31); identity s-layout, all loads f32x4.
  {
    const int cb = kg;                            // col-block 0..3
    const float* Sr = S + ((size_t)src << 7) + cb * 32;
    const float* Tr = T + ((size_t)dst << 7) + cb * 32;
    const float* Wr = swl2f + cb * 32;
#pragma unroll
    for (int q = 0; q < 4; ++q) {
      f32x4 s0 = *(const f32x4*)(Sr + q * 8);
      f32x4 s1 = *(const f32x4*)(Sr + q * 8 + 4);
      f32x4 t0 = *(const f32x4*)(Tr + q * 8);
      f32x4 t1 = *(const f32x4*)(Tr + q * 8 + 4);
      f32x4 w0 = *(const f32x4*)(Wr + q * 8);
      f32x4 w1 = *(const f32x4*)(Wr + q * 8 + 4);
      u32x4 w;
      float v0, v1;
      v0 = ftanh(s0[0] + t0[0] + l2 * w0[0]);
      v1 = ftanh(s0[1] + t0[1] + l2 * w0[1]);
      w[0] = pk2(v0, v1);
      v0 = ftanh(s0[2] + t0[2] + l2 * w0[2]);
      v1 = ftanh(s0[3] + t0[3] + l2 * w0[3]);
      w[1] = pk2(v0, v1);
      v0 = ftanh(s1[0] + t1[0] + l2 * w1[0]);
      v1 = ftanh(s1[1] + t1[1] + l2 * w1[1]);
      w[2] = pk2(v0, v1);
      v0 = ftanh(s1[2] + t1[2] + l2 * w1[2]);
      v1 = ftanh(s1[3] + t1[3] + l2 * w1[3]);
      w[3] = pk2(v0, v1);
      int row = xrow0 + cl;
      *(u32x4*)((char*)Xs + row * 256 + ((cb * 64 + q * 16) ^ ((row & 7) << 4))) = w;
    }
  }

  // ---- layer 2: m1 @ W2 (A from LDS identity layout, B natural k-order) ----
  ZERO8;
#pragma unroll
  for (int ks = 0; ks < 4; ++ks) {
    short8 a = xs_read(Xs, xrow0 + cl, ks * 64 + kg * 16);
#pragma unroll
    for (int nt = 0; nt < 8; ++nt) {
      short8 b = bfrag(OFF_W2_HI, ks, nt, lane);
      acc[nt] = MFMA(a, b, acc[nt], 0, 0, 0);
    }
  }

  // ---- epi 2: tanh+bias, gate, m_i, gated m -> Xs (perm layout) ----
  {
    float wac[8], b2c[8];
#pragma unroll
    for (int nt = 0; nt < 8; ++nt) {
      wac[nt] = swaf[nt * 16 + cl];
      b2c[nt] = sb2f[nt * 16 + cl];
    }
#pragma unroll
    for (int nt = 0; nt < 8; ++nt)
#pragma unroll
      for (int reg = 0; reg < 4; ++reg)
        acc[nt][reg] = ftanh(acc[nt][reg] + b2c[nt]);
    float p[4];
#pragma unroll
    for (int reg = 0; reg < 4; ++reg) {
      float s = 0.f;
#pragma unroll
      for (int nt = 0; nt < 8; ++nt) s = fmaf(acc[nt][reg], wac[nt], s);
      p[reg] = s;
    }
#pragma unroll
    for (int m = 1; m <= 8; m <<= 1)
#pragma unroll
      for (int reg = 0; reg < 4; ++reg) p[reg] += __shfl_xor(p[reg], m);
    float g[4];
#pragma unroll
    for (int reg = 0; reg < 4; ++reg) g[reg] = fsigmoid(p[reg] + ba_s);
#pragma unroll
    for (int nt = 0; nt < 8; ++nt)
#pragma unroll
      for (int reg = 0; reg < 4; ++reg) acc[nt][reg] *= g[reg];
    float cs[8];
#pragma unroll
    for (int nt = 0; nt < 8; ++nt) {
      cs[nt] = (acc[nt][0] + acc[nt][1]) + (acc[nt][2] + acc[nt][3]);
      cs[nt] += __shfl_xor(cs[nt], 16);
      cs[nt] += __shfl_xor(cs[nt], 32);
    }
    {  // m_i hi/lo store, all 64 lanes (2 cols each)
      int g4 = lane >> 4;
      size_t base = (size_t)dst * 128 + cl;
#pragma unroll
      for (int e2 = 0; e2 < 2; ++e2) {
        int nt = g4 * 2 + e2;
        float s = cs[nt];
        unsigned short hh = f2bf(s);
        Mh[base + nt * 16] = hh;
        Ml[base + nt * 16] = f2bf(s - bf2f(hh));
      }
    }
    float vv[4][8];
#pragma unroll
    for (int nt = 0; nt < 8; ++nt)
#pragma unroll
      for (int reg = 0; reg < 4; ++reg) vv[reg][nt] = acc[nt][reg];
#pragma unroll
    for (int reg = 0; reg < 4; ++reg) xs_write8(Xs, xrow0 + kg * 4 + reg, cl, vv[reg]);
  }

  // ---- layer 3: m @ Wc1 (A from LDS perm layout, B perm k-order) ----
  ZERO8;
#pragma unroll
  for (int ks = 0; ks < 4; ++ks) {
    short8 a = xs_read(Xs, xrow0 + cl, ks * 64 + kg * 16);
#pragma unroll
    for (int nt = 0; nt < 8; ++nt) {
      short8 b = bfrag(OFF_WC1_HI, ks, nt, lane);
      acc[nt] = MFMA(a, b, acc[nt], 0, 0, 0);
    }
  }

  // ---- epi 3: c2 = tanh(tanh(acc+bc1).Wc2); coords segment-sum ----
  {
    float wcc[8], bcc[8];
#pragma unroll
    for (int nt = 0; nt < 8; ++nt) {
      wcc[nt] = swc2f[nt * 16 + cl];
      bcc[nt] = sbc1f[nt * 16 + cl];
    }
    float p[4];
#pragma unroll
    for (int reg = 0; reg < 4; ++reg) {
      float s = 0.f;
#pragma unroll
      for (int nt = 0; nt < 8; ++nt)
        s = fmaf(ftanh(acc[nt][reg] + bcc[nt]), wcc[nt], s);
      p[reg] = s;
    }
#pragma unroll
    for (int m = 1; m <= 8; m <<= 1)
#pragma unroll
      for (int reg = 0; reg < 4; ++reg) p[reg] += __shfl_xor(p[reg], m);
    float st = 0.f;
#pragma unroll
    for (int reg = 0; reg < 4; ++reg) {
      int sl = kg * 4 + reg;
      float vx = __shfl(dx, sl), vy = __shfl(dy, sl), vz = __shfl(dz, sl);
      float cmp = ((cl & 3) == 1) ? vy : (((cl & 3) == 2) ? vz : vx);
      st = fmaf(cmp, ftanh(p[reg]), st);
    }
    st += __shfl_xor(st, 16);
    st += __shfl_xor(st, 32);
    if (lane < 3)
      coords_out[dst * 3 + lane] = coords[dst * 3 + lane] + st * 0.0625f;
  }
}

// ------- node: block = 16 rows x 4 waves (2 nt-tiles each); one barrier -------
__global__ __launch_bounds__(256) void node_kernel(
    const float* __restrict__ hidden, const unsigned short* __restrict__ Mh,
    const unsigned short* __restrict__ Ml, const float* __restrict__ bh1,
    const float* __restrict__ bh2, float* __restrict__ hidden_out, int N) {
  __shared__ __align__(16) unsigned short Xs[16 * 128];   // 4 KB
  const int tid = threadIdx.x, wid = tid >> 6, lane = tid & 63;
  const int cl = lane & 15, kg = lane >> 4;
  const int n0 = blockIdx.x * 16;
  const int rmin = min(n0 + cl, N - 1);
  const f32x4 vzero = {0.f, 0.f, 0.f, 0.f};
  f32x4 acc[2];
  ZERO2(acc);
  // layer 1 half 0: hidden (f32, convert in-register)
  {
    const float* Arow = hidden + ((size_t)rmin << 7);
#pragma unroll
    for (int ks = 0; ks < 4; ++ks) {
      float x[8];
      *(f32x4*)&x[0] = *(const f32x4*)(Arow + ks * 32 + kg * 8);
      *(f32x4*)&x[4] = *(const f32x4*)(Arow + ks * 32 + kg * 8 + 4);
      short8 ah, al;
      mk8(x, ah, al);
#pragma unroll
      for (int q = 0; q < 2; ++q) {
        int nt = wid * 2 + q;
        short8 bh = bfrag(OFF_WH1_HI, ks, nt, lane);
        short8 bl = bfrag(OFF_WH1_LO, ks, nt, lane);
        acc[q] = MFMA(ah, bh, acc[q], 0, 0, 0);
        acc[q] = MFMA(al, bh, acc[q], 0, 0, 0);
        acc[q] = MFMA(ah, bl, acc[q], 0, 0, 0);
      }
    }
  }
  // layer 1 half 1: m_i (bf16 hi/lo planes)
  {
    const int prow = rmin << 7;
#pragma unroll
    for (int ks = 0; ks < 4; ++ks) {
      short8 ah = *(const short8*)(Mh + prow + ks * 32 + kg * 8);
      short8 al = *(const short8*)(Ml + prow + ks * 32 + kg * 8);
#pragma unroll
      for (int q = 0; q < 2; ++q) {
        int nt = wid * 2 + q;
        short8 bh = bfrag(OFF_WH1_HI, 4 + ks, nt, lane);
        short8 bl = bfrag(OFF_WH1_LO, 4 + ks, nt, lane);
        acc[q] = MFMA(ah, bh, acc[q], 0, 0, 0);
        acc[q] = MFMA(al, bh, acc[q], 0, 0, 0);
        acc[q] = MFMA(ah, bl, acc[q], 0, 0, 0);
      }
    }
  }
  // epi 1: h1 = tanh(acc + bh1) -> Xs (perm s-layout: s = cl*8 + nt)
  {
    float bv0 = bh1[(wid * 2 + 0) * 16 + cl];
    float bv1 = bh1[(wid * 2 + 1) * 16 + cl];
#pragma unroll
    for (int reg = 0; reg < 4; ++reg) {
      int row = kg * 4 + reg;
      unsigned int w = pk2(ftanh(acc[0][reg] + bv0), ftanh(acc[1][reg] + bv1));
      *(unsigned int*)((char*)Xs + row * 256 + ((cl * 16 + wid * 4) ^ ((row & 7) << 4))) = w;
    }
  }
  __syncthreads();
  // layer 2: h1 @ Wh2 (A full rows from LDS, B perm k-order)
  ZERO2(acc);
#pragma unroll
  for (int ks = 0; ks < 4; ++ks) {
    short8 a = xs_read(Xs, cl, ks * 64 + kg * 16);
#pragma unroll
    for (int q = 0; q < 2; ++q) {
      short8 b = bfrag(OFF_WH2_HI, ks, wid * 2 + q, lane);
      acc[q] = MFMA(a, b, acc[q], 0, 0, 0);
    }
  }
  // epi 2: hidden_out = hidden + acc + bh2
#pragma unroll
  for (int q = 0; q < 2; ++q) {
    int nt = wid * 2 + q;
    float bv = bh2[nt * 16 + cl];
#pragma unroll
    for (int reg = 0; reg < 4; ++reg) {
      int rw = n0 + kg * 4 + reg;
      if (rw < N) {
        size_t o = (size_t)rw * 128 + nt * 16 + cl;
        hidden_out[o] = hidden[o] + acc[q][reg] + bv;
      }
    }
  }
}

extern "C" void kernel_launch(void* const* d_in, const int* in_sizes, int n_in,
                              void* d_out, int out_size, void* d_ws, size_t ws_size,
                              hipStream_t stream) {
  const float* coords = (const float*)d_in[0];
  const float* hidden = (const float*)d_in[1];
  const int* edges = (const int*)d_in[2];
  const float* W1 = (const float*)d_in[3];
  const float* b1 = (const float*)d_in[4];
  const float* W2 = (const float*)d_in[5];
  const float* b2 = (const float*)d_in[6];
  const float* Wa = (const float*)d_in[7];
  const float* ba = (const float*)d_in[8];
  const float* Wc1 = (const float*)d_in[9];
  const float* bc1 = (const float*)d_in[10];
  const float* Wc2 = (const float*)d_in[11];
  const float* Wh1 = (const float*)d_in[12];
  const float* bh1 = (const float*)d_in[13];
  const float* Wh2 = (const float*)d_in[14];
  const float* bh2 = (const float*)d_in[15];

  const int N = in_sizes[0] / 3;   // 30000
  const int E = in_sizes[2] / 2;   // 480000

  float* T = (float*)d_ws;                                    // [N,128] f32
  float* S = T + (size_t)N * 128;                             // [N,128] f32
  unsigned short* Mh = (unsigned short*)(S + (size_t)N * 128);
  unsigned short* Ml = Mh + (size_t)N * 128;
  float* coords_out = (float*)d_out;                          // [N,3]
  float* hidden_out = coords_out + (size_t)N * 3;             // [N,128]

  wconv_kernel<<<448, 256, 0, stream>>>(W1, W2, Wc1, Wh1, Wh2);
  const int nb16 = (N + 15) / 16;
  st_kernel<<<nb16, 256, 0, stream>>>(hidden, b1, S, T, N);
  edge_kernel<<<E / 64, 256, 0, stream>>>(coords, edges, W1, b2, Wa, ba, bc1, Wc2,
                                          T, S, Mh, Ml, coords_out, E);
  node_kernel<<<nb16, 256, 0, stream>>>(hidden, Mh, Ml, bh1, bh2, hidden_out, N);
}

// Round 8
// 252.977 us; speedup vs baseline: 6.7218x; 1.0132x over previous
//
#include <hip/hip_runtime.h>
#include <hip/hip_bf16.h>
#include <math.h>

// EGNN layer, bf16-MFMA v8 (XCD-chunked swizzle + st/node ILP):
//  R7 counters: edge FETCH 46.6MB vs ~20 ideal -> S/T rows re-fetched across
//  XCD L2s (round-robin block->XCD); each miss ~900cyc. st/node ~125us for
//  ~10us of work (low per-wave ILP, B-frags reloaded per 16 rows).
//  v8:
//   - bijective XCD-chunked swizzle (q=nblk/8,r=nblk%8) on edge/st/node:
//     each XCD gets a contiguous block range -> its S/T slice (~1.9MB) is
//     L2-resident; st and edge chunks cover the SAME node range -> S/T can
//     stay in L2 across kernels.
//   - st/node: 32 rows/block (2 row-tiles/wave, B-frag shared across both)
//     -> 2x frag reuse + 2x ILP; grid 938.
//  Numerics identical to R7 (absmax must stay exactly 0.03125).
// Carried invariants: hi+lo split for W1A/W1B/Wh1 + A-operands; W2 natural
// k-order (epi1 identity layout); Wc1/Wh2 perm k-order (s=cl*8+nt);
// Xs swizzle byte ^= ((row&7)<<4); edge wave = 16 edges = 1 dst.

typedef __attribute__((ext_vector_type(8))) short short8;
typedef __attribute__((ext_vector_type(4))) float f32x4;
typedef __attribute__((ext_vector_type(4))) unsigned int u32x4;

#define MFMA __builtin_amdgcn_mfma_f32_16x16x32_bf16

// u16-unit offsets into g_frags (each kt-chunk = 4096 u16)
#define OFF_W1A_HI 0
#define OFF_W1A_LO 16384
#define OFF_W1B_HI 32768
#define OFF_W1B_LO 49152
#define OFF_W2_HI  65536
#define OFF_WC1_HI 81920
#define OFF_WH1_HI 98304
#define OFF_WH1_LO 131072
#define OFF_WH2_HI 163840
#define FRAG_TOTAL 180224

__device__ __align__(16) unsigned short g_frags[FRAG_TOTAL];

#define DEVFN static __device__ __forceinline__

// bijective XCD-chunked remap: hardware sends blockIdx b to XCD b%8;
// give XCD x the contiguous work chunk so its working set is L2-resident.
DEVFN int xcd_swz(int bid, int nblk) {
  int q = nblk >> 3, r = nblk & 7;
  int x = bid & 7, i = bid >> 3;
  int start = (x < r) ? x * (q + 1) : r * (q + 1) + (x - r) * q;
  return start + i;
}

DEVFN unsigned short f2bf(float x) {  // fp32 -> bf16 RNE
  unsigned int u = __float_as_uint(x);
  u += 0x7fffu + ((u >> 16) & 1u);
  return (unsigned short)(u >> 16);
}
DEVFN float bf2f(unsigned short h) { return __uint_as_float(((unsigned int)h) << 16); }

DEVFN unsigned int pk2(float a, float b) {  // -> packed bf16x2 (a=low), RNE
  __hip_bfloat162 p = __float22bfloat162_rn(make_float2(a, b));
  union { __hip_bfloat162 h; unsigned int u; } cv;
  cv.h = p;
  return cv.u;
}

DEVFN float fexp2(float x) {
  float r;
  asm volatile("v_exp_f32 %0, %1" : "=v"(r) : "v"(x));
  return r;
}
DEVFN float frcp(float x) {
  float r;
  asm volatile("v_rcp_f32 %0, %1" : "=v"(r) : "v"(x));
  return r;
}
DEVFN float ftanh(float x) {  // 1 - 2/(e^{2x}+1); saturates at +/-1
  return 1.0f - 2.0f * frcp(fexp2(x * 2.8853900817779268f) + 1.0f);
}
DEVFN float fsigmoid(float x) {
  return frcp(1.0f + fexp2(-x * 1.4426950408889634f));
}

// 8 consecutive f32 -> bf16 hi/lo fragments (packed cvt pairs)
DEVFN void mk8(const float* __restrict__ x, short8& hi, short8& lo) {
  unsigned int hp[4], lp[4];
#pragma unroll
  for (int q = 0; q < 4; ++q) hp[q] = pk2(x[2 * q], x[2 * q + 1]);
#pragma unroll
  for (int q = 0; q < 4; ++q) {
    float f0 = __uint_as_float(hp[q] << 16);
    float f1 = __uint_as_float(hp[q] & 0xffff0000u);
    lp[q] = pk2(x[2 * q] - f0, x[2 * q + 1] - f1);
  }
  union { u32x4 u; short8 s; } ch, clo;
  ch.u[0] = hp[0]; ch.u[1] = hp[1]; ch.u[2] = hp[2]; ch.u[3] = hp[3];
  clo.u[0] = lp[0]; clo.u[1] = lp[1]; clo.u[2] = lp[2]; clo.u[3] = lp[3];
  hi = ch.s; lo = clo.s;
}

DEVFN short8 bfrag(int off_u16, int kt, int nt, int lane) {
  return *(const short8*)(g_frags + off_u16 + (((kt << 3) + nt) << 9) + (lane << 3));
}

// swizzled bf16 LDS tile: row-major [R][128] u16, byte ^= ((row&7)<<4)
DEVFN short8 xs_read(const unsigned short* Xs, int row, int sbyte) {
  return *(const short8*)((const char*)Xs + row * 256 + (sbyte ^ ((row & 7) << 4)));
}
DEVFN void xs_write8(unsigned short* Xs, int row, int cl, const float* v) {
  u32x4 w;
  w[0] = pk2(v[0], v[1]); w[1] = pk2(v[2], v[3]);
  w[2] = pk2(v[4], v[5]); w[3] = pk2(v[6], v[7]);
  *(u32x4*)((char*)Xs + row * 256 + ((cl << 4) ^ ((row & 7) << 4))) = w;
}

#define ZERO8 { _Pragma("unroll") for (int nt = 0; nt < 8; ++nt) acc[nt] = vzero; }
#define ZERO22(a) { _Pragma("unroll") for (int rt = 0; rt < 2; ++rt) \
                    _Pragma("unroll") for (int q = 0; q < 2; ++q) (a)[rt][q] = vzero; }

// ---------------- wconv: all weight planes, one launch ----------------
__global__ __launch_bounds__(256) void wconv_kernel(const float* __restrict__ W1,
                                                    const float* __restrict__ W2,
                                                    const float* __restrict__ Wc1,
                                                    const float* __restrict__ Wh1,
                                                    const float* __restrict__ Wh2) {
  int t = blockIdx.x * 256 + threadIdx.x;
  if (t >= 28 * 4096) return;
  int seg = t >> 12, r = t & 4095;
  int j = r & 7, lane = (r >> 3) & 63, nt = (r >> 9) & 7;
  int kg = lane >> 4, cl = lane & 15;
  const float* src; int kt, offH, offL, perm;
  if (seg < 4)       { src = W1;             kt = seg;      offH = OFF_W1A_HI; offL = OFF_W1A_LO; perm = 0; }
  else if (seg < 8)  { src = W1 + 128 * 128; kt = seg - 4;  offH = OFF_W1B_HI; offL = OFF_W1B_LO; perm = 0; }
  else if (seg < 12) { src = W2;             kt = seg - 8;  offH = OFF_W2_HI;  offL = -1;         perm = 0; }
  else if (seg < 16) { src = Wc1;            kt = seg - 12; offH = OFF_WC1_HI; offL = -1;         perm = 1; }
  else if (seg < 24) { src = Wh1;            kt = seg - 16; offH = OFF_WH1_HI; offL = OFF_WH1_LO; perm = 0; }
  else               { src = Wh2;            kt = seg - 24; offH = OFF_WH2_HI; offL = -1;         perm = 1; }
  int ke = kt * 32 + kg * 8 + j;
  int k = perm ? ((ke & 7) * 16 + (ke >> 3)) : ke;
  float w = src[k * 128 + nt * 16 + cl];
  unsigned short h = f2bf(w);
  int fi = kt * 4096 + nt * 512 + lane * 8 + j;
  g_frags[offH + fi] = h;
  if (offL >= 0) g_frags[offL + fi] = f2bf(w - bf2f(h));
}

// -------- st: S = hidden@W1A, T = hidden@W1B + b1; block = 32 rows x 4 waves --------
__global__ __launch_bounds__(256) void st_kernel(const float* __restrict__ hidden,
                                                 const float* __restrict__ b1,
                                                 float* __restrict__ S,
                                                 float* __restrict__ T, int N) {
  const int tid = threadIdx.x, wid = tid >> 6, lane = tid & 63;
  const int cl = lane & 15, kg = lane >> 4;
  const int n0 = xcd_swz(blockIdx.x, gridDim.x) * 32;
  const float* Arow0 = hidden + ((size_t)min(n0 + cl, N - 1) << 7);
  const float* Arow1 = hidden + ((size_t)min(n0 + 16 + cl, N - 1) << 7);
  const f32x4 vzero = {0.f, 0.f, 0.f, 0.f};
  f32x4 accS[2][2], accT[2][2];
  ZERO22(accS); ZERO22(accT);
#pragma unroll
  for (int ks = 0; ks < 4; ++ks) {
    short8 ah[2], al[2];
    {
      float x[8];
      *(f32x4*)&x[0] = *(const f32x4*)(Arow0 + ks * 32 + kg * 8);
      *(f32x4*)&x[4] = *(const f32x4*)(Arow0 + ks * 32 + kg * 8 + 4);
      mk8(x, ah[0], al[0]);
      *(f32x4*)&x[0] = *(const f32x4*)(Arow1 + ks * 32 + kg * 8);
      *(f32x4*)&x[4] = *(const f32x4*)(Arow1 + ks * 32 + kg * 8 + 4);
      mk8(x, ah[1], al[1]);
    }
#pragma unroll
    for (int q = 0; q < 2; ++q) {
      int nt = wid * 2 + q;
      short8 bh = bfrag(OFF_W1A_HI, ks, nt, lane);
      short8 bl = bfrag(OFF_W1A_LO, ks, nt, lane);
#pragma unroll
      for (int rt = 0; rt < 2; ++rt) {
        accS[rt][q] = MFMA(ah[rt], bh, accS[rt][q], 0, 0, 0);
        accS[rt][q] = MFMA(al[rt], bh, accS[rt][q], 0, 0, 0);
        accS[rt][q] = MFMA(ah[rt], bl, accS[rt][q], 0, 0, 0);
      }
      bh = bfrag(OFF_W1B_HI, ks, nt, lane);
      bl = bfrag(OFF_W1B_LO, ks, nt, lane);
#pragma unroll
      for (int rt = 0; rt < 2; ++rt) {
        accT[rt][q] = MFMA(ah[rt], bh, accT[rt][q], 0, 0, 0);
        accT[rt][q] = MFMA(al[rt], bh, accT[rt][q], 0, 0, 0);
        accT[rt][q] = MFMA(ah[rt], bl, accT[rt][q], 0, 0, 0);
      }
    }
  }
#pragma unroll
  for (int q = 0; q < 2; ++q) {
    int nt = wid * 2 + q;
    float bv = b1[nt * 16 + cl];
#pragma unroll
    for (int rt = 0; rt < 2; ++rt)
#pragma unroll
      for (int reg = 0; reg < 4; ++reg) {
        int rw = n0 + rt * 16 + kg * 4 + reg;
        if (rw < N) {
          size_t o = (size_t)rw * 128 + nt * 16 + cl;
          S[o] = accS[rt][q][reg];
          T[o] = accT[rt][q][reg] + bv;
        }
      }
  }
}

// ------- edge: 256 thr = 4 waves; wave = 16 edges = 1 dst -------
__global__ __launch_bounds__(256) void edge_kernel(
    const float* __restrict__ coords, const int* __restrict__ edges,
    const float* __restrict__ W1, const float* __restrict__ b2,
    const float* __restrict__ Wa, const float* __restrict__ ba,
    const float* __restrict__ bc1, const float* __restrict__ Wc2,
    const float* __restrict__ T, const float* __restrict__ S,
    unsigned short* __restrict__ Mh, unsigned short* __restrict__ Ml,
    float* __restrict__ coords_out, int E) {
  __shared__ __align__(16) unsigned short Xs[64 * 128];   // 16 KB, wave-private slices
  __shared__ __align__(16) float swl2f[128];
  __shared__ float swaf[128], swc2f[128], sb2f[128], sbc1f[128];  // 2.5 KB total

  const int tid = threadIdx.x, wid = tid >> 6, lane = tid & 63;
  const int cl = lane & 15, kg = lane >> 4;
  const int xrow0 = wid * 16;
  const int bid = xcd_swz(blockIdx.x, gridDim.x);
  const int e0 = bid * 64 + wid * 16;            // 16 edges, one dst group

  if (tid < 128) {
    swl2f[tid] = W1[256 * 128 + tid];
    swaf[tid] = Wa[tid];
    swc2f[tid] = Wc2[tid];
    sb2f[tid] = b2[tid];
    sbc1f[tid] = bc1[tid];
  }
  __syncthreads();

  const int dst = edges[E + e0];                 // wave-uniform
  const int src = edges[e0 + cl];                // row cl's source node
  const float cx = coords[3 * dst], cy = coords[3 * dst + 1], cz = coords[3 * dst + 2];
  const float dx = coords[3 * src] - cx, dy = coords[3 * src + 1] - cy, dz = coords[3 * src + 2] - cz;
  const float l2 = sqrtf(dx * dx + dy * dy + dz * dz);
  const float ba_s = ba[0];

  const f32x4 vzero = {0.f, 0.f, 0.f, 0.f};
  f32x4 acc[8];

  // ---- epi 1 (vectorized): m1 = tanh(S[src] + T[dst] + l2*wl2) -> Xs ----
  {
    const int cb = kg;                            // col-block 0..3
    const float* Sr = S + ((size_t)src << 7) + cb * 32;
    const float* Tr = T + ((size_t)dst << 7) + cb * 32;
    const float* Wr = swl2f + cb * 32;
#pragma unroll
    for (int q = 0; q < 4; ++q) {
      f32x4 s0 = *(const f32x4*)(Sr + q * 8);
      f32x4 s1 = *(const f32x4*)(Sr + q * 8 + 4);
      f32x4 t0 = *(const f32x4*)(Tr + q * 8);
      f32x4 t1 = *(const f32x4*)(Tr + q * 8 + 4);
      f32x4 w0 = *(const f32x4*)(Wr + q * 8);
      f32x4 w1 = *(const f32x4*)(Wr + q * 8 + 4);
      u32x4 w;
      float v0, v1;
      v0 = ftanh(s0[0] + t0[0] + l2 * w0[0]);
      v1 = ftanh(s0[1] + t0[1] + l2 * w0[1]);
      w[0] = pk2(v0, v1);
      v0 = ftanh(s0[2] + t0[2] + l2 * w0[2]);
      v1 = ftanh(s0[3] + t0[3] + l2 * w0[3]);
      w[1] = pk2(v0, v1);
      v0 = ftanh(s1[0] + t1[0] + l2 * w1[0]);
      v1 = ftanh(s1[1] + t1[1] + l2 * w1[1]);
      w[2] = pk2(v0, v1);
      v0 = ftanh(s1[2] + t1[2] + l2 * w1[2]);
      v1 = ftanh(s1[3] + t1[3] + l2 * w1[3]);
      w[3] = pk2(v0, v1);
      int row = xrow0 + cl;
      *(u32x4*)((char*)Xs + row * 256 + ((cb * 64 + q * 16) ^ ((row & 7) << 4))) = w;
    }
  }

  // ---- layer 2: m1 @ W2 (A from LDS identity layout, B natural k-order) ----
  ZERO8;
#pragma unroll
  for (int ks = 0; ks < 4; ++ks) {
    short8 a = xs_read(Xs, xrow0 + cl, ks * 64 + kg * 16);
#pragma unroll
    for (int nt = 0; nt < 8; ++nt) {
      short8 b = bfrag(OFF_W2_HI, ks, nt, lane);
      acc[nt] = MFMA(a, b, acc[nt], 0, 0, 0);
    }
  }

  // ---- epi 2: tanh+bias, gate, m_i, gated m -> Xs (perm layout) ----
  {
    float wac[8], b2c[8];
#pragma unroll
    for (int nt = 0; nt < 8; ++nt) {
      wac[nt] = swaf[nt * 16 + cl];
      b2c[nt] = sb2f[nt * 16 + cl];
    }
#pragma unroll
    for (int nt = 0; nt < 8; ++nt)
#pragma unroll
      for (int reg = 0; reg < 4; ++reg)
        acc[nt][reg] = ftanh(acc[nt][reg] + b2c[nt]);
    float p[4];
#pragma unroll
    for (int reg = 0; reg < 4; ++reg) {
      float s = 0.f;
#pragma unroll
      for (int nt = 0; nt < 8; ++nt) s = fmaf(acc[nt][reg], wac[nt], s);
      p[reg] = s;
    }
#pragma unroll
    for (int m = 1; m <= 8; m <<= 1)
#pragma unroll
      for (int reg = 0; reg < 4; ++reg) p[reg] += __shfl_xor(p[reg], m);
    float g[4];
#pragma unroll
    for (int reg = 0; reg < 4; ++reg) g[reg] = fsigmoid(p[reg] + ba_s);
#pragma unroll
    for (int nt = 0; nt < 8; ++nt)
#pragma unroll
      for (int reg = 0; reg < 4; ++reg) acc[nt][reg] *= g[reg];
    float cs[8];
#pragma unroll
    for (int nt = 0; nt < 8; ++nt) {
      cs[nt] = (acc[nt][0] + acc[nt][1]) + (acc[nt][2] + acc[nt][3]);
      cs[nt] += __shfl_xor(cs[nt], 16);
      cs[nt] += __shfl_xor(cs[nt], 32);
    }
    {  // m_i hi/lo store, all 64 lanes (2 cols each)
      int g4 = lane >> 4;
      size_t base = (size_t)dst * 128 + cl;
#pragma unroll
      for (int e2 = 0; e2 < 2; ++e2) {
        int nt = g4 * 2 + e2;
        float s = cs[nt];
        unsigned short hh = f2bf(s);
        Mh[base + nt * 16] = hh;
        Ml[base + nt * 16] = f2bf(s - bf2f(hh));
      }
    }
    float vv[4][8];
#pragma unroll
    for (int nt = 0; nt < 8; ++nt)
#pragma unroll
      for (int reg = 0; reg < 4; ++reg) vv[reg][nt] = acc[nt][reg];
#pragma unroll
    for (int reg = 0; reg < 4; ++reg) xs_write8(Xs, xrow0 + kg * 4 + reg, cl, vv[reg]);
  }

  // ---- layer 3: m @ Wc1 (A from LDS perm layout, B perm k-order) ----
  ZERO8;
#pragma unroll
  for (int ks = 0; ks < 4; ++ks) {
    short8 a = xs_read(Xs, xrow0 + cl, ks * 64 + kg * 16);
#pragma unroll
    for (int nt = 0; nt < 8; ++nt) {
      short8 b = bfrag(OFF_WC1_HI, ks, nt, lane);
      acc[nt] = MFMA(a, b, acc[nt], 0, 0, 0);
    }
  }

  // ---- epi 3: c2 = tanh(tanh(acc+bc1).Wc2); coords segment-sum ----
  {
    float wcc[8], bcc[8];
#pragma unroll
    for (int nt = 0; nt < 8; ++nt) {
      wcc[nt] = swc2f[nt * 16 + cl];
      bcc[nt] = sbc1f[nt * 16 + cl];
    }
    float p[4];
#pragma unroll
    for (int reg = 0; reg < 4; ++reg) {
      float s = 0.f;
#pragma unroll
      for (int nt = 0; nt < 8; ++nt)
        s = fmaf(ftanh(acc[nt][reg] + bcc[nt]), wcc[nt], s);
      p[reg] = s;
    }
#pragma unroll
    for (int m = 1; m <= 8; m <<= 1)
#pragma unroll
      for (int reg = 0; reg < 4; ++reg) p[reg] += __shfl_xor(p[reg], m);
    float st = 0.f;
#pragma unroll
    for (int reg = 0; reg < 4; ++reg) {
      int sl = kg * 4 + reg;
      float vx = __shfl(dx, sl), vy = __shfl(dy, sl), vz = __shfl(dz, sl);
      float cmp = ((cl & 3) == 1) ? vy : (((cl & 3) == 2) ? vz : vx);
      st = fmaf(cmp, ftanh(p[reg]), st);
    }
    st += __shfl_xor(st, 16);
    st += __shfl_xor(st, 32);
    if (lane < 3)
      coords_out[dst * 3 + lane] = coords[dst * 3 + lane] + st * 0.0625f;
  }
}

// ------- node: block = 32 rows x 4 waves (2 nt-tiles each); one barrier -------
__global__ __launch_bounds__(256) void node_kernel(
    const float* __restrict__ hidden, const unsigned short* __restrict__ Mh,
    const unsigned short* __restrict__ Ml, const float* __restrict__ bh1,
    const float* __restrict__ bh2, float* __restrict__ hidden_out, int N) {
  __shared__ __align__(16) unsigned short Xs[32 * 128];   // 8 KB
  const int tid = threadIdx.x, wid = tid >> 6, lane = tid & 63;
  const int cl = lane & 15, kg = lane >> 4;
  const int n0 = xcd_swz(blockIdx.x, gridDim.x) * 32;
  const int r0 = min(n0 + cl, N - 1);
  const int r1 = min(n0 + 16 + cl, N - 1);
  const f32x4 vzero = {0.f, 0.f, 0.f, 0.f};
  f32x4 acc[2][2];
  ZERO22(acc);
  // layer 1 half 0: hidden (f32, convert in-register)
  {
    const float* A0 = hidden + ((size_t)r0 << 7);
    const float* A1 = hidden + ((size_t)r1 << 7);
#pragma unroll
    for (int ks = 0; ks < 4; ++ks) {
      short8 ah[2], al[2];
      float x[8];
      *(f32x4*)&x[0] = *(const f32x4*)(A0 + ks * 32 + kg * 8);
      *(f32x4*)&x[4] = *(const f32x4*)(A0 + ks * 32 + kg * 8 + 4);
      mk8(x, ah[0], al[0]);
      *(f32x4*)&x[0] = *(const f32x4*)(A1 + ks * 32 + kg * 8);
      *(f32x4*)&x[4] = *(const f32x4*)(A1 + ks * 32 + kg * 8 + 4);
      mk8(x, ah[1], al[1]);
#pragma unroll
      for (int q = 0; q < 2; ++q) {
        int nt = wid * 2 + q;
        short8 bh = bfrag(OFF_WH1_HI, ks, nt, lane);
        short8 bl = bfrag(OFF_WH1_LO, ks, nt, lane);
#pragma unroll
        for (int rt = 0; rt < 2; ++rt) {
          acc[rt][q] = MFMA(ah[rt], bh, acc[rt][q], 0, 0, 0);
          acc[rt][q] = MFMA(al[rt], bh, acc[rt][q], 0, 0, 0);
          acc[rt][q] = MFMA(ah[rt], bl, acc[rt][q], 0, 0, 0);
        }
      }
    }
  }
  // layer 1 half 1: m_i (bf16 hi/lo planes)
  {
    const int p0 = r0 << 7, p1 = r1 << 7;
#pragma unroll
    for (int ks = 0; ks < 4; ++ks) {
      short8 ah[2], al[2];
      ah[0] = *(const short8*)(Mh + p0 + ks * 32 + kg * 8);
      al[0] = *(const short8*)(Ml + p0 + ks * 32 + kg * 8);
      ah[1] = *(const short8*)(Mh + p1 + ks * 32 + kg * 8);
      al[1] = *(const short8*)(Ml + p1 + ks * 32 + kg * 8);
#pragma unroll
      for (int q = 0; q < 2; ++q) {
        int nt = wid * 2 + q;
        short8 bh = bfrag(OFF_WH1_HI, 4 + ks, nt, lane);
        short8 bl = bfrag(OFF_WH1_LO, 4 + ks, nt, lane);
#pragma unroll
        for (int rt = 0; rt < 2; ++rt) {
          acc[rt][q] = MFMA(ah[rt], bh, acc[rt][q], 0, 0, 0);
          acc[rt][q] = MFMA(al[rt], bh, acc[rt][q], 0, 0, 0);
          acc[rt][q] = MFMA(ah[rt], bl, acc[rt][q], 0, 0, 0);
        }
      }
    }
  }
  // epi 1: h1 = tanh(acc + bh1) -> Xs (perm s-layout: s = cl*8 + nt)
  {
    float bv0 = bh1[(wid * 2 + 0) * 16 + cl];
    float bv1 = bh1[(wid * 2 + 1) * 16 + cl];
#pragma unroll
    for (int rt = 0; rt < 2; ++rt)
#pragma unroll
      for (int reg = 0; reg < 4; ++reg) {
        int row = rt * 16 + kg * 4 + reg;
        unsigned int w = pk2(ftanh(acc[rt][0][reg] + bv0), ftanh(acc[rt][1][reg] + bv1));
        *(unsigned int*)((char*)Xs + row * 256 + ((cl * 16 + wid * 4) ^ ((row & 7) << 4))) = w;
      }
  }
  __syncthreads();
  // layer 2: h1 @ Wh2 (A full rows from LDS, B perm k-order)
  ZERO22(acc);
#pragma unroll
  for (int ks = 0; ks < 4; ++ks) {
    short8 a0 = xs_read(Xs, cl, ks * 64 + kg * 16);
    short8 a1 = xs_read(Xs, 16 + cl, ks * 64 + kg * 16);
#pragma unroll
    for (int q = 0; q < 2; ++q) {
      short8 b = bfrag(OFF_WH2_HI, ks, wid * 2 + q, lane);
      acc[0][q] = MFMA(a0, b, acc[0][q], 0, 0, 0);
      acc[1][q] = MFMA(a1, b, acc[1][q], 0, 0, 0);
    }
  }
  // epi 2: hidden_out = hidden + acc + bh2
#pragma unroll
  for (int q = 0; q < 2; ++q) {
    int nt = wid * 2 + q;
    float bv = bh2[nt * 16 + cl];
#pragma unroll
    for (int rt = 0; rt < 2; ++rt)
#pragma unroll
      for (int reg = 0; reg < 4; ++reg) {
        int rw = n0 + rt * 16 + kg * 4 + reg;
        if (rw < N) {
          size_t o = (size_t)rw * 128 + nt * 16 + cl;
          hidden_out[o] = hidden[o] + acc[rt][q][reg] + bv;
        }
      }
  }
}

extern "C" void kernel_launch(void* const* d_in, const int* in_sizes, int n_in,
                              void* d_out, int out_size, void* d_ws, size_t ws_size,
                              hipStream_t stream) {
  const float* coords = (const float*)d_in[0];
  const float* hidden = (const float*)d_in[1];
  const int* edges = (const int*)d_in[2];
  const float* W1 = (const float*)d_in[3];
  const float* b1 = (const float*)d_in[4];
  const float* W2 = (const float*)d_in[5];
  const float* b2 = (const float*)d_in[6];
  const float* Wa = (const float*)d_in[7];
  const float* ba = (const float*)d_in[8];
  const float* Wc1 = (const float*)d_in[9];
  const float* bc1 = (const float*)d_in[10];
  const float* Wc2 = (const float*)d_in[11];
  const float* Wh1 = (const float*)d_in[12];
  const float* bh1 = (const float*)d_in[13];
  const float* Wh2 = (const float*)d_in[14];
  const float* bh2 = (const float*)d_in[15];

  const int N = in_sizes[0] / 3;   // 30000
  const int E = in_sizes[2] / 2;   // 480000

  float* T = (float*)d_ws;                                    // [N,128] f32
  float* S = T + (size_t)N * 128;                             // [N,128] f32
  unsigned short* Mh = (unsigned short*)(S + (size_t)N * 128);
  unsigned short* Ml = Mh + (size_t)N * 128;
  float* coords_out = (float*)d_out;                          // [N,3]
  float* hidden_out = coords_out + (size_t)N * 3;             // [N,128]

  wconv_kernel<<<448, 256, 0, stream>>>(W1, W2, Wc1, Wh1, Wh2);
  const int nb32 = (N + 31) / 32;
  st_kernel<<<nb32, 256, 0, stream>>>(hidden, b1, S, T, N);
  edge_kernel<<<E / 64, 256, 0, stream>>>(coords, edges, W1, b2, Wa, ba, bc1, Wc2,
                                          T, S, Mh, Ml, coords_out, E);
  node_kernel<<<nb32, 256, 0, stream>>>(hidden, Mh, Ml, bh1, bh2, hidden_out, N);
}